// Round 12
// baseline (212.879 us; speedup 1.0000x reference)
//
#include <hip/hip_runtime.h>
#include <hip/hip_bf16.h>
#include <cfloat>

#define N1C 50176
#define N2C 12544
#define N3C 3136

typedef __attribute__((ext_vector_type(8))) short short8v;
typedef __attribute__((ext_vector_type(4))) float f32x4;

static __device__ __forceinline__ unsigned short f2bf(float f){
  __hip_bfloat16 h = __float2bfloat16(f);
  return *reinterpret_cast<unsigned short*>(&h);
}
static __device__ __forceinline__ float bflo(unsigned v){
  return __uint_as_float(v << 16);
}
static __device__ __forceinline__ float bfhi(unsigned v){
  return __uint_as_float(v & 0xFFFF0000u);
}
static __device__ __forceinline__ float bf2f(unsigned short u){
  return __uint_as_float(((unsigned)u) << 16);
}
static __device__ __forceinline__ unsigned pk2(float a, float b){
  return (unsigned)f2bf(a) | ((unsigned)f2bf(b) << 16);
}

// ---------------- transpose x: (16,3,N1) f32 -> xTb (N1, 16, 4) bf16 ----
__global__ __launch_bounds__(256) void transpose_x_kernel(
    const float* __restrict__ x, unsigned short* __restrict__ xTb)
{
  __shared__ float tile[48][65];
  int n0 = blockIdx.x * 64;
  int tid = threadIdx.x;
  int i = tid & 63;
  for (int rr = tid >> 6; rr < 48; rr += 4)
    tile[rr][i] = x[(size_t)rr * N1C + n0 + i];
  __syncthreads();
  for (int j = tid; j < 64*64; j += 256){
    int ii = j >> 6, bc = j & 63, b = bc >> 2, c = bc & 3;
    float v = (c < 3) ? tile[b*3 + c][ii] : 0.f;
    xTb[(size_t)n0 * 64 + j] = f2bf(v);
  }
}

// ---------------- A[n,k,t] = (relu(off @ w1 + b1) @ w2 + b2) ----------------
__global__ __launch_bounds__(256) void compute_A_kernel(
    const float* __restrict__ pos_in, const float* __restrict__ pos_out,
    const int* __restrict__ idx,
    const float* __restrict__ w1, const float* __restrict__ b1,
    const float* __restrict__ w2, const float* __restrict__ b2,
    float* __restrict__ Abuf)
{
  int g = blockIdx.x * 256 + threadIdx.x;
  if (g >= N2C * 9) return;
  int n = g / 9;
  int p = idx[g];
  float o0 = pos_in[2*p]   - pos_out[2*n];
  float o1 = pos_in[2*p+1] - pos_out[2*n+1];
  float A[9];
  #pragma unroll
  for (int t = 0; t < 9; t++) A[t] = b2[t];
  #pragma unroll
  for (int j = 0; j < 16; j++){
    float h = fmaxf(fmaf(o0, w1[j], fmaf(o1, w1[16+j], b1[j])), 0.f);
    #pragma unroll
    for (int t = 0; t < 9; t++) A[t] = fmaf(h, w2[j*9 + t], A[t]);
  }
  #pragma unroll
  for (int t = 0; t < 9; t++) Abuf[(size_t)g*9 + t] = A[t];
}

// ------ W (o,c,t) f32 -> Wb bf16. mode0: Wb[o][k=c*9+t] pad to KW.
// ------ mode1: Wb[o][k'=t*32+c] (t-major permutation, K=KW=288).
__global__ __launch_bounds__(256) void wcvt_kernel(
    const float* __restrict__ W, unsigned short* __restrict__ Wb,
    int total, int K, int KW, int mode)
{
  int i = blockIdx.x * 256 + threadIdx.x;
  if (i >= total) return;
  int o = i / KW, r = i % KW;
  float v;
  if (mode == 0){
    v = (r < K) ? W[o*K + r] : 0.f;
  } else {
    int t = r >> 5, c = r & 31;          // r = t*32 + c
    v = W[o*288 + c*9 + t];
  }
  Wb[i] = f2bf(v);
}

// ======== conv1 path (small CIN), linear k-layout ========
template<int CIN, int CINP, int COUT, int NPB, bool AFFINE>
__global__ __launch_bounds__(256) void conv_mfma_kernel(
    const unsigned short* __restrict__ in, const int* __restrict__ idx,
    const float* __restrict__ Abuf, const unsigned short* __restrict__ Wb,
    const float* __restrict__ bias,
    const float* __restrict__ scale, const float* __restrict__ shift,
    unsigned short* __restrict__ out, float* __restrict__ gpart)
{
  constexpr int K    = CIN * 9;
  constexpr int KW   = (K < 32) ? 32 : K;
  constexpr int KROW = (K < 32) ? 48 : 296;
  constexpr int CHUNKS = KW / 32;
  constexpr int OT   = COUT / 16;
  constexpr int HP   = CINP / 2;
  constexpr int PPT  = 16 * HP;

  __shared__ alignas(16) unsigned short Tb[NPB * 16 * KROW];
  __shared__ float As[NPB * 81];
  __shared__ int   Ip[NPB * 9];
  __shared__ float Sw[4 * COUT];
  __shared__ float Sq[4 * COUT];

  int n0 = blockIdx.x * NPB;
  int tid = threadIdx.x;
  for (int i = tid; i < NPB*81; i += 256) As[i] = Abuf[(size_t)n0*81 + i];
  if (tid < NPB*9) Ip[tid] = idx[n0*9 + tid];
  for (int i = tid; i < 4*COUT; i += 256){ Sw[i] = 0.f; Sq[i] = 0.f; }
  if (K < 32){
    for (int i = tid; i < NPB*16*KROW/2; i += 256) ((unsigned*)Tb)[i] = 0u;
  }
  __syncthreads();

  for (int u = tid; u < NPB*PPT; u += 256){
    int ni = u / PPT, loc = u % PPT;
    int b = loc / HP, c2 = loc % HP;
    const float* As_n = As + ni*81;
    const int*   ip   = Ip + ni*9;
    float scx=1.f, shx=0.f, scy=1.f, shy=0.f;
    if (AFFINE){
      scx = scale[2*c2];   shx = shift[2*c2];
      scy = scale[2*c2+1]; shy = shift[2*c2+1];
    }
    float fx[9], fy[9];
    #pragma unroll
    for (int k = 0; k < 9; k++){
      unsigned v = *(const unsigned*)(in + ((size_t)ip[k]*16 + b)*CINP + 2*c2);
      float x0 = bflo(v), y0 = bfhi(v);
      if (AFFINE){
        x0 = fmaxf(fmaf(x0, scx, shx), 0.f);
        y0 = fmaxf(fmaf(y0, scy, shy), 0.f);
      }
      fx[k] = x0; fy[k] = y0;
    }
    unsigned short e[18];
    #pragma unroll
    for (int t = 0; t < 9; t++){
      float s0 = 0.f, s1 = 0.f;
      #pragma unroll
      for (int k = 0; k < 9; k++){
        float a = As_n[k*9 + t];
        s0 = fmaf(fx[k], a, s0);
        s1 = fmaf(fy[k], a, s1);
      }
      e[t] = f2bf(s0); e[9+t] = f2bf(s1);
    }
    unsigned* dst = (unsigned*)(Tb + (ni*16 + b)*KROW + 18*c2);
    #pragma unroll
    for (int j = 0; j < 9; j++) dst[j] = (unsigned)e[2*j] | ((unsigned)e[2*j+1] << 16);
  }
  __syncthreads();

  int w = tid >> 6, l = tid & 63, lr = l & 15, lg = l >> 4;
  float smr[4] = {0,0,0,0}, sqr[4] = {0,0,0,0};
  int oBase = 0;
  for (int wi = w; wi < NPB*OT; wi += 4){
    int ni = wi / OT, ot = wi % OT;
    oBase = 16*ot + 4*lg;
    f32x4 acc;
    #pragma unroll
    for (int r = 0; r < 4; r++) acc[r] = bias[oBase + r];
    const short8v* ap = (const short8v*)(Wb + (size_t)(16*ot + lr)*KW) + lg;
    const short8v* bp = (const short8v*)(Tb + (ni*16 + lr)*KROW) + lg;
    #pragma unroll
    for (int kk = 0; kk < CHUNKS; kk++)
      acc = __builtin_amdgcn_mfma_f32_16x16x32_bf16(ap[kk*4], bp[kk*4], acc, 0, 0, 0);
    ushort4 o4;
    o4.x = f2bf(acc[0]); o4.y = f2bf(acc[1]); o4.z = f2bf(acc[2]); o4.w = f2bf(acc[3]);
    *(ushort4*)(out + ((size_t)(n0 + ni)*16 + lr)*COUT + oBase) = o4;
    #pragma unroll
    for (int r = 0; r < 4; r++){
      smr[r] += acc[r];
      sqr[r] = fmaf(acc[r], acc[r], sqr[r]);
    }
  }
  #pragma unroll
  for (int m = 1; m < 16; m <<= 1){
    #pragma unroll
    for (int r = 0; r < 4; r++){
      smr[r] += __shfl_xor(smr[r], m);
      sqr[r] += __shfl_xor(sqr[r], m);
    }
  }
  if (lr == 0){
    #pragma unroll
    for (int r = 0; r < 4; r++){
      Sw[w*COUT + oBase + r] = smr[r];
      Sq[w*COUT + oBase + r] = sqr[r];
    }
  }
  __syncthreads();
  for (int o = tid; o < COUT; o += 256){
    float sm = Sw[o] + Sw[COUT + o] + Sw[2*COUT + o] + Sw[3*COUT + o];
    float sq = Sq[o] + Sq[COUT + o] + Sq[2*COUT + o] + Sq[3*COUT + o];
    gpart[(size_t)blockIdx.x * 2*COUT + o] = sm;
    gpart[(size_t)blockIdx.x * 2*COUT + COUT + o] = sq;
  }
}

// ======== conv2/3: wave-per-point, 4-point pipelined loop ========
// Pipeline: issue point p+1's gathers+A-loads, sched_barrier, compute point p.
// All hot state in NAMED registers (macros) to prevent scratch demotion.

#define GATHER9(R0,R1,R2,R3,R4,R5,R6,R7,R8, NWS) { \
  const int* ipr_ = idx + (size_t)(NWS)*9; \
  R0 = *(const uint4*)(gbase + (size_t)ipr_[0]*512); \
  R1 = *(const uint4*)(gbase + (size_t)ipr_[1]*512); \
  R2 = *(const uint4*)(gbase + (size_t)ipr_[2]*512); \
  R3 = *(const uint4*)(gbase + (size_t)ipr_[3]*512); \
  R4 = *(const uint4*)(gbase + (size_t)ipr_[4]*512); \
  R5 = *(const uint4*)(gbase + (size_t)ipr_[5]*512); \
  R6 = *(const uint4*)(gbase + (size_t)ipr_[6]*512); \
  R7 = *(const uint4*)(gbase + (size_t)ipr_[7]*512); \
  R8 = *(const uint4*)(gbase + (size_t)ipr_[8]*512); }

#define ALOAD(A0,A1, NWS) { const float* Ap_ = Abuf + (size_t)(NWS)*81; \
  A0 = Ap_[l]; A1 = (l < 17) ? Ap_[64 + l] : 0.f; }

#define AWRITE(A0,A1) { int k_ = l/9, t_ = l - k_*9; Aw[k_*12 + t_] = A0; \
  if (l < 17){ int j_ = l + 64; int k2_ = j_/9, t2_ = j_ - k2_*9; Aw[k2_*12 + t2_] = A1; } }

#define LOX(P) (P).x
#define LOY(P) (P).y
#define HIZ(P) (P).z
#define HIW(P) (P).w

#define TKSTEP(PK, K, S0, S1, SC, SH) { \
  unsigned u0_ = S0(PK), u1_ = S1(PK); \
  f32x4 f_; f_[0]=bflo(u0_); f_[1]=bfhi(u0_); f_[2]=bflo(u1_); f_[3]=bfhi(u1_); \
  f_ = f_ * (SC) + (SH); \
  f_[0]=fmaxf(f_[0],0.f); f_[1]=fmaxf(f_[1],0.f); f_[2]=fmaxf(f_[2],0.f); f_[3]=fmaxf(f_[3],0.f); \
  f32x4 a03_ = *(const f32x4*)(Aw + (K)*12); \
  f32x4 a47_ = *(const f32x4*)(Aw + (K)*12 + 4); \
  float a8_ = Aw[(K)*12 + 8]; \
  tv0 += f_ * a03_[0]; tv1 += f_ * a03_[1]; tv2 += f_ * a03_[2]; tv3 += f_ * a03_[3]; \
  tv4 += f_ * a47_[0]; tv5 += f_ * a47_[1]; tv6 += f_ * a47_[2]; tv7 += f_ * a47_[3]; \
  tv8 += f_ * a8_; }

#define TSTORE(TV, T, DH) { uint2 o_; o_.x = pk2(TV[0],TV[1]); o_.y = pk2(TV[2],TV[3]); \
  *(uint2*)((DH) + (T)*32) = o_; }

#define TAPS_HALF(P0,P1,P2,P3,P4,P5,P6,P7,P8, S0,S1, SC,SH, DOFF) { \
  f32x4 tv0={0,0,0,0},tv1={0,0,0,0},tv2={0,0,0,0},tv3={0,0,0,0},tv4={0,0,0,0}, \
        tv5={0,0,0,0},tv6={0,0,0,0},tv7={0,0,0,0},tv8={0,0,0,0}; \
  TKSTEP(P0,0,S0,S1,SC,SH) TKSTEP(P1,1,S0,S1,SC,SH) TKSTEP(P2,2,S0,S1,SC,SH) \
  TKSTEP(P3,3,S0,S1,SC,SH) TKSTEP(P4,4,S0,S1,SC,SH) TKSTEP(P5,5,S0,S1,SC,SH) \
  TKSTEP(P6,6,S0,S1,SC,SH) TKSTEP(P7,7,S0,S1,SC,SH) TKSTEP(P8,8,S0,S1,SC,SH) \
  unsigned short* dh_ = drow + (DOFF); \
  TSTORE(tv0,0,dh_) TSTORE(tv1,1,dh_) TSTORE(tv2,2,dh_) TSTORE(tv3,3,dh_) \
  TSTORE(tv4,4,dh_) TSTORE(tv5,5,dh_) TSTORE(tv6,6,dh_) TSTORE(tv7,7,dh_) TSTORE(tv8,8,dh_) }

#define TAPS9(P0,P1,P2,P3,P4,P5,P6,P7,P8) { \
  TAPS_HALF(P0,P1,P2,P3,P4,P5,P6,P7,P8, LOX,LOY, sc4A,sh4A, 0) \
  TAPS_HALF(P0,P1,P2,P3,P4,P5,P6,P7,P8, HIZ,HIW, sc4B,sh4B, 4) }

#define PHASE3(NWS) { \
  _Pragma("unroll") \
  for (int ot = 0; ot < OT; ot++){ \
    int oBase = 16*ot + 4*lg; \
    f32x4 a3; a3[0]=bias[oBase]; a3[1]=bias[oBase+1]; a3[2]=bias[oBase+2]; a3[3]=bias[oBase+3]; \
    const short8v* ap_ = (const short8v*)(Wb + (size_t)(16*ot + lr)*288) + lg; \
    _Pragma("unroll") \
    for (int kk = 0; kk < 9; kk++) \
      a3 = __builtin_amdgcn_mfma_f32_16x16x32_bf16(ap_[kk*4], bp[kk*4], a3, 0, 0, 0); \
    ushort4 o4_; o4_.x=f2bf(a3[0]); o4_.y=f2bf(a3[1]); o4_.z=f2bf(a3[2]); o4_.w=f2bf(a3[3]); \
    *(ushort4*)(out + ((size_t)(NWS)*16 + lr)*COUT + oBase) = o4_; \
    if (ot==0){ sm0 += a3; sq0 += a3*a3; } \
    else if (ot==1){ sm1 += a3; sq1 += a3*a3; } \
    else if (ot==2){ sm2 += a3; sq2 += a3*a3; } \
    else { sm3 += a3; sq3 += a3*a3; } } }

template<int COUT>
__global__ __launch_bounds__(256, 2) void conv_wave_kernel(
    const unsigned short* __restrict__ in, const int* __restrict__ idx,
    const float* __restrict__ Abuf, const unsigned short* __restrict__ Wb,
    const float* __restrict__ bias,
    const float* __restrict__ scale, const float* __restrict__ shift,
    unsigned short* __restrict__ out, float* __restrict__ gpart)
{
  constexpr int NPB  = 4;              // waves per block
  constexpr int PPW  = 4;              // points per wave (pipelined)
  constexpr int PPB  = NPB * PPW;      // 16 points per block
  constexpr int KROW = 296;
  constexpr int OT   = COUT / 16;
  constexpr int USZ  = 128;            // per-wave union slot: A(108) / stats(2*COUT)

  __shared__ alignas(16) unsigned short Tb[NPB * 16 * KROW];  // 37,888 B
  __shared__ alignas(16) float U[NPB * USZ];                  //  2,048 B

  int tid = threadIdx.x;
  int w = tid >> 6, l = tid & 63;
  int base = blockIdx.x * PPB + w * PPW;

  int b = l & 15, cg = l >> 4;
  int lr = b, lg = cg;
  const unsigned short* gbase = in + b*32 + cg*8;
  float* Aw = U + w * USZ;
  unsigned short* drow = Tb + (size_t)(w*16 + b)*KROW + cg*8;
  const short8v* bp = (const short8v*)(Tb + (size_t)(w*16 + lr)*KROW) + lg;

  float4 scA_ = *(const float4*)(scale + cg*8);
  float4 scB_ = *(const float4*)(scale + cg*8 + 4);
  float4 shA_ = *(const float4*)(shift + cg*8);
  float4 shB_ = *(const float4*)(shift + cg*8 + 4);
  f32x4 sc4A; sc4A[0]=scA_.x; sc4A[1]=scA_.y; sc4A[2]=scA_.z; sc4A[3]=scA_.w;
  f32x4 sh4A; sh4A[0]=shA_.x; sh4A[1]=shA_.y; sh4A[2]=shA_.z; sh4A[3]=shA_.w;
  f32x4 sc4B; sc4B[0]=scB_.x; sc4B[1]=scB_.y; sc4B[2]=scB_.z; sc4B[3]=scB_.w;
  f32x4 sh4B; sh4B[0]=shB_.x; sh4B[1]=shB_.y; sh4B[2]=shB_.z; sh4B[3]=shB_.w;

  f32x4 sm0={0,0,0,0}, sm1={0,0,0,0}, sm2={0,0,0,0}, sm3={0,0,0,0};
  f32x4 sq0={0,0,0,0}, sq1={0,0,0,0}, sq2={0,0,0,0}, sq3={0,0,0,0};

  uint4 rA0,rA1,rA2,rA3,rA4,rA5,rA6,rA7,rA8;
  uint4 rB0,rB1,rB2,rB3,rB4,rB5,rB6,rB7,rB8;
  float a0_, a1_;

  // ---- prologue: point 0 ----
  int nws0 = __builtin_amdgcn_readfirstlane(base + 0);
  ALOAD(a0_, a1_, nws0);
  GATHER9(rA0,rA1,rA2,rA3,rA4,rA5,rA6,rA7,rA8, nws0);
  AWRITE(a0_, a1_);

  // ---- p = 0 (compute rA; prefetch point 1 -> rB) ----
  int nws1 = __builtin_amdgcn_readfirstlane(base + 1);
  ALOAD(a0_, a1_, nws1);
  GATHER9(rB0,rB1,rB2,rB3,rB4,rB5,rB6,rB7,rB8, nws1);
  __builtin_amdgcn_sched_barrier(0);
  TAPS9(rA0,rA1,rA2,rA3,rA4,rA5,rA6,rA7,rA8);
  AWRITE(a0_, a1_);
  PHASE3(nws0);

  // ---- p = 1 (compute rB; prefetch point 2 -> rA) ----
  int nws2 = __builtin_amdgcn_readfirstlane(base + 2);
  ALOAD(a0_, a1_, nws2);
  GATHER9(rA0,rA1,rA2,rA3,rA4,rA5,rA6,rA7,rA8, nws2);
  __builtin_amdgcn_sched_barrier(0);
  TAPS9(rB0,rB1,rB2,rB3,rB4,rB5,rB6,rB7,rB8);
  AWRITE(a0_, a1_);
  PHASE3(nws1);

  // ---- p = 2 (compute rA; prefetch point 3 -> rB) ----
  int nws3 = __builtin_amdgcn_readfirstlane(base + 3);
  ALOAD(a0_, a1_, nws3);
  GATHER9(rB0,rB1,rB2,rB3,rB4,rB5,rB6,rB7,rB8, nws3);
  __builtin_amdgcn_sched_barrier(0);
  TAPS9(rA0,rA1,rA2,rA3,rA4,rA5,rA6,rA7,rA8);
  AWRITE(a0_, a1_);
  PHASE3(nws2);

  // ---- p = 3 (compute rB; no prefetch) ----
  TAPS9(rB0,rB1,rB2,rB3,rB4,rB5,rB6,rB7,rB8);
  PHASE3(nws3);

  // ---- stats: one reduce at the end; U slot (A dead) becomes staging ----
  #pragma unroll
  for (int ot = 0; ot < OT; ot++){
    f32x4 s = (ot==0) ? sm0 : ((ot==1) ? sm1 : ((ot==2) ? sm2 : sm3));
    f32x4 q = (ot==0) ? sq0 : ((ot==1) ? sq1 : ((ot==2) ? sq2 : sq3));
    #pragma unroll
    for (int m = 1; m < 16; m <<= 1){
      #pragma unroll
      for (int r = 0; r < 4; r++){
        s[r] += __shfl_xor(s[r], m);
        q[r] += __shfl_xor(q[r], m);
      }
    }
    if (lr == 0){
      int oBase = 16*ot + 4*lg;
      #pragma unroll
      for (int r = 0; r < 4; r++){
        U[w*USZ + oBase + r]        = s[r];
        U[w*USZ + COUT + oBase + r] = q[r];
      }
    }
  }
  __syncthreads();
  for (int o = tid; o < COUT; o += 256){
    float smv = U[o] + U[USZ + o] + U[2*USZ + o] + U[3*USZ + o];
    float sqv = U[COUT + o] + U[USZ + COUT + o] + U[2*USZ + COUT + o] + U[3*USZ + COUT + o];
    gpart[(size_t)blockIdx.x * 2*COUT + o] = smv;
    gpart[(size_t)blockIdx.x * 2*COUT + COUT + o] = sqv;
  }
}

// ---------------- finalize BN ----------------
__global__ __launch_bounds__(256) void bn_finalize_kernel(
    const float* __restrict__ gpart, int NB, int C,
    const float* __restrict__ g, const float* __restrict__ bb,
    float* __restrict__ sc, float* __restrict__ sh, float invN)
{
  int c = blockIdx.x;
  float sm = 0.f, sq = 0.f;
  for (int i = threadIdx.x; i < NB; i += 256){
    sm += gpart[(size_t)i*2*C + c];
    sq += gpart[(size_t)i*2*C + C + c];
  }
  #pragma unroll
  for (int off = 32; off > 0; off >>= 1){
    sm += __shfl_down(sm, off);
    sq += __shfl_down(sq, off);
  }
  __shared__ float rs[8];
  int wd = threadIdx.x >> 6, ln = threadIdx.x & 63;
  if (ln == 0){ rs[wd] = sm; rs[4+wd] = sq; }
  __syncthreads();
  if (threadIdx.x == 0){
    float S = rs[0]+rs[1]+rs[2]+rs[3], Q = rs[4]+rs[5]+rs[6]+rs[7];
    float mean = S * invN;
    float var  = fmaxf(Q * invN - mean*mean, 0.f);
    float s = g[c] * rsqrtf(var + 1e-5f);
    sc[c] = s;
    sh[c] = bb[c] - mean * s;
  }
}

// ------------- BN3 + relu + max-pool + write (16,64,N3) f32 -------------
__global__ __launch_bounds__(256) void pool_kernel(
    const unsigned short* __restrict__ h3, const int* __restrict__ pidx,
    const float* __restrict__ sc, const float* __restrict__ sh,
    float* __restrict__ out)
{
  __shared__ float P[16][1024];
  int m0 = blockIdx.x * 16;
  int tid = threadIdx.x;
  for (int mi = 0; mi < 16; mi++){
    int m = m0 + mi;
    int p0 = pidx[m*4+0], p1 = pidx[m*4+1], p2 = pidx[m*4+2], p3 = pidx[m*4+3];
    #pragma unroll
    for (int q = 0; q < 4; q++){
      int bo = tid + q*256;
      int o = bo & 63;
      float s = sc[o], h = sh[o];
      float v0 = fmaf(bf2f(h3[(size_t)p0*1024 + bo]), s, h);
      float v1 = fmaf(bf2f(h3[(size_t)p1*1024 + bo]), s, h);
      float v2 = fmaf(bf2f(h3[(size_t)p2*1024 + bo]), s, h);
      float v3 = fmaf(bf2f(h3[(size_t)p3*1024 + bo]), s, h);
      P[mi][bo] = fmaxf(fmaxf(fmaxf(v0,v1), fmaxf(v2,v3)), 0.f);
    }
  }
  __syncthreads();
  #pragma unroll
  for (int w = 0; w < 4; w++){
    int r = tid + w*256;
    float* dst = out + (size_t)r*N3C + m0;
    #pragma unroll
    for (int mi = 0; mi < 16; mi++) dst[mi] = P[mi][r];
  }
}

// ---------------- launch ----------------
extern "C" void kernel_launch(void* const* d_in, const int* in_sizes, int n_in,
                              void* d_out, int out_size, void* d_ws, size_t ws_size,
                              hipStream_t stream)
{
  const float* x    = (const float*)d_in[0];
  const float* l1   = (const float*)d_in[1];
  const float* l2   = (const float*)d_in[2];
  const int* knn1   = (const int*)d_in[4];
  const int* knn2   = (const int*)d_in[5];
  const int* knn3   = (const int*)d_in[6];
  const int* pidx   = (const int*)d_in[7];

  const float* c1_w1 = (const float*)d_in[8];
  const float* c1_b1 = (const float*)d_in[9];
  const float* c1_w2 = (const float*)d_in[10];
  const float* c1_b2 = (const float*)d_in[11];
  const float* c1_k  = (const float*)d_in[12];
  const float* c1_bs = (const float*)d_in[13];
  const float* c2_w1 = (const float*)d_in[14];
  const float* c2_b1 = (const float*)d_in[15];
  const float* c2_w2 = (const float*)d_in[16];
  const float* c2_b2 = (const float*)d_in[17];
  const float* c2_k  = (const float*)d_in[18];
  const float* c2_bs = (const float*)d_in[19];
  const float* c3_w1 = (const float*)d_in[20];
  const float* c3_b1 = (const float*)d_in[21];
  const float* c3_w2 = (const float*)d_in[22];
  const float* c3_b2 = (const float*)d_in[23];
  const float* c3_k  = (const float*)d_in[24];
  const float* c3_bs = (const float*)d_in[25];
  const float* bn1_g = (const float*)d_in[26];
  const float* bn1_b = (const float*)d_in[27];
  const float* bn2_g = (const float*)d_in[28];
  const float* bn2_b = (const float*)d_in[29];
  const float* bn3_g = (const float*)d_in[30];
  const float* bn3_b = (const float*)d_in[31];

  char* ws = (char*)d_ws;
  unsigned short* xTb = (unsigned short*)(ws + 0);
  unsigned short* h1  = (unsigned short*)(ws + 6422528);
  unsigned short* h2  = (unsigned short*)(ws + 19267584);
  unsigned short* h3  = (unsigned short*)(ws + 32112640);
  float* Abuf         = (float*)(ws + 57802752);
  float* gpart        = (float*)(ws + 61867008);
  unsigned short* wb1 = (unsigned short*)(ws + 65078272);
  unsigned short* wb2 = (unsigned short*)(ws + 65081344);
  unsigned short* wb3 = (unsigned short*)(ws + 65099776);
  float* sc1 = (float*)(ws + 65137664); float* sh1 = sc1 + 32;
  float* sc2 = sh1 + 32;                float* sh2 = sc2 + 32;
  float* sc3 = sh2 + 32;                float* sh3 = sc3 + 64;

  const float invN = 1.0f / (float)(N2C * 16);
  const int ablocks = (N2C * 9 + 255) / 256;
  const int cwblocks = N2C / 16;   // 784

  transpose_x_kernel<<<N1C/64, 256, 0, stream>>>(x, xTb);
  wcvt_kernel<<<(32*32 + 255)/256, 256, 0, stream>>>(c1_k, wb1, 32*32, 27, 32, 0);
  wcvt_kernel<<<(32*288 + 255)/256, 256, 0, stream>>>(c2_k, wb2, 32*288, 288, 288, 1);
  wcvt_kernel<<<(64*288 + 255)/256, 256, 0, stream>>>(c3_k, wb3, 64*288, 288, 288, 1);

  // conv1
  compute_A_kernel<<<ablocks, 256, 0, stream>>>(l1, l2, knn1, c1_w1, c1_b1, c1_w2, c1_b2, Abuf);
  conv_mfma_kernel<3, 4, 32, 8, false><<<N2C/8, 256, 0, stream>>>(
      xTb, knn1, Abuf, wb1, c1_bs, nullptr, nullptr, h1, gpart);
  bn_finalize_kernel<<<32, 256, 0, stream>>>(gpart, N2C/8, 32, bn1_g, bn1_b, sc1, sh1, invN);

  // conv2
  compute_A_kernel<<<ablocks, 256, 0, stream>>>(l2, l2, knn2, c2_w1, c2_b1, c2_w2, c2_b2, Abuf);
  conv_wave_kernel<32><<<cwblocks, 256, 0, stream>>>(
      h1, knn2, Abuf, wb2, c2_bs, sc1, sh1, h2, gpart);
  bn_finalize_kernel<<<32, 256, 0, stream>>>(gpart, cwblocks, 32, bn2_g, bn2_b, sc2, sh2, invN);

  // conv3
  compute_A_kernel<<<ablocks, 256, 0, stream>>>(l2, l2, knn3, c3_w1, c3_b1, c3_w2, c3_b2, Abuf);
  conv_wave_kernel<64><<<cwblocks, 256, 0, stream>>>(
      h2, knn3, Abuf, wb3, c3_bs, sc2, sh2, h3, gpart);
  bn_finalize_kernel<<<64, 256, 0, stream>>>(gpart, cwblocks, 64, bn3_g, bn3_b, sc3, sh3, invN);

  pool_kernel<<<N3C/16, 256, 0, stream>>>(h3, pidx, sc3, sh3, (float*)d_out);
}

// Round 13
// 171.074 us; speedup vs baseline: 1.2444x; 1.2444x over previous
//
#include <hip/hip_runtime.h>
#include <hip/hip_bf16.h>
#include <cfloat>

#define N1C 50176
#define N2C 12544
#define N3C 3136

typedef __attribute__((ext_vector_type(8))) short short8v;
typedef __attribute__((ext_vector_type(4))) float f32x4;

static __device__ __forceinline__ unsigned short f2bf(float f){
  __hip_bfloat16 h = __float2bfloat16(f);
  return *reinterpret_cast<unsigned short*>(&h);
}
static __device__ __forceinline__ float bflo(unsigned v){
  return __uint_as_float(v << 16);
}
static __device__ __forceinline__ float bfhi(unsigned v){
  return __uint_as_float(v & 0xFFFF0000u);
}
static __device__ __forceinline__ float bf2f(unsigned short u){
  return __uint_as_float(((unsigned)u) << 16);
}
static __device__ __forceinline__ unsigned pk2(float a, float b){
  return (unsigned)f2bf(a) | ((unsigned)f2bf(b) << 16);
}
// pack 8 f32 (lo half L, hi half H) -> one bf16 B-fragment (4 VGPRs)
static __device__ __forceinline__ short8v pack8(f32x4 L, f32x4 H){
  short8v r;
  r[0]=(short)f2bf(L[0]); r[1]=(short)f2bf(L[1]); r[2]=(short)f2bf(L[2]); r[3]=(short)f2bf(L[3]);
  r[4]=(short)f2bf(H[0]); r[5]=(short)f2bf(H[1]); r[6]=(short)f2bf(H[2]); r[7]=(short)f2bf(H[3]);
  return r;
}

// ---------------- transpose x: (16,3,N1) f32 -> xTb (N1, 16, 4) bf16 ----
__global__ __launch_bounds__(256) void transpose_x_kernel(
    const float* __restrict__ x, unsigned short* __restrict__ xTb)
{
  __shared__ float tile[48][65];
  int n0 = blockIdx.x * 64;
  int tid = threadIdx.x;
  int i = tid & 63;
  for (int rr = tid >> 6; rr < 48; rr += 4)
    tile[rr][i] = x[(size_t)rr * N1C + n0 + i];
  __syncthreads();
  for (int j = tid; j < 64*64; j += 256){
    int ii = j >> 6, bc = j & 63, b = bc >> 2, c = bc & 3;
    float v = (c < 3) ? tile[b*3 + c][ii] : 0.f;
    xTb[(size_t)n0 * 64 + j] = f2bf(v);
  }
}

// ---------------- A[n,k,t] = (relu(off @ w1 + b1) @ w2 + b2) ----------------
__global__ __launch_bounds__(256) void compute_A_kernel(
    const float* __restrict__ pos_in, const float* __restrict__ pos_out,
    const int* __restrict__ idx,
    const float* __restrict__ w1, const float* __restrict__ b1,
    const float* __restrict__ w2, const float* __restrict__ b2,
    float* __restrict__ Abuf)
{
  int g = blockIdx.x * 256 + threadIdx.x;
  if (g >= N2C * 9) return;
  int n = g / 9;
  int p = idx[g];
  float o0 = pos_in[2*p]   - pos_out[2*n];
  float o1 = pos_in[2*p+1] - pos_out[2*n+1];
  float A[9];
  #pragma unroll
  for (int t = 0; t < 9; t++) A[t] = b2[t];
  #pragma unroll
  for (int j = 0; j < 16; j++){
    float h = fmaxf(fmaf(o0, w1[j], fmaf(o1, w1[16+j], b1[j])), 0.f);
    #pragma unroll
    for (int t = 0; t < 9; t++) A[t] = fmaf(h, w2[j*9 + t], A[t]);
  }
  #pragma unroll
  for (int t = 0; t < 9; t++) Abuf[(size_t)g*9 + t] = A[t];
}

// ------ W (o,c,t) f32 -> Wb bf16. mode0: Wb[o][k=c*9+t] pad to KW.
// ------ mode1: Wb[o][k'=t*32+c] (t-major permutation, K=KW=288).
__global__ __launch_bounds__(256) void wcvt_kernel(
    const float* __restrict__ W, unsigned short* __restrict__ Wb,
    int total, int K, int KW, int mode)
{
  int i = blockIdx.x * 256 + threadIdx.x;
  if (i >= total) return;
  int o = i / KW, r = i % KW;
  float v;
  if (mode == 0){
    v = (r < K) ? W[o*K + r] : 0.f;
  } else {
    int t = r >> 5, c = r & 31;          // r = t*32 + c
    v = W[o*288 + c*9 + t];
  }
  Wb[i] = f2bf(v);
}

// ======== conv1 path (small CIN), linear k-layout ========
template<int CIN, int CINP, int COUT, int NPB, bool AFFINE>
__global__ __launch_bounds__(256) void conv_mfma_kernel(
    const unsigned short* __restrict__ in, const int* __restrict__ idx,
    const float* __restrict__ Abuf, const unsigned short* __restrict__ Wb,
    const float* __restrict__ bias,
    const float* __restrict__ scale, const float* __restrict__ shift,
    unsigned short* __restrict__ out, float* __restrict__ gpart)
{
  constexpr int K    = CIN * 9;
  constexpr int KW   = (K < 32) ? 32 : K;
  constexpr int KROW = (K < 32) ? 48 : 296;
  constexpr int CHUNKS = KW / 32;
  constexpr int OT   = COUT / 16;
  constexpr int HP   = CINP / 2;
  constexpr int PPT  = 16 * HP;

  __shared__ alignas(16) unsigned short Tb[NPB * 16 * KROW];
  __shared__ float As[NPB * 81];
  __shared__ int   Ip[NPB * 9];
  __shared__ float Sw[4 * COUT];
  __shared__ float Sq[4 * COUT];

  int n0 = blockIdx.x * NPB;
  int tid = threadIdx.x;
  for (int i = tid; i < NPB*81; i += 256) As[i] = Abuf[(size_t)n0*81 + i];
  if (tid < NPB*9) Ip[tid] = idx[n0*9 + tid];
  for (int i = tid; i < 4*COUT; i += 256){ Sw[i] = 0.f; Sq[i] = 0.f; }
  if (K < 32){
    for (int i = tid; i < NPB*16*KROW/2; i += 256) ((unsigned*)Tb)[i] = 0u;
  }
  __syncthreads();

  for (int u = tid; u < NPB*PPT; u += 256){
    int ni = u / PPT, loc = u % PPT;
    int b = loc / HP, c2 = loc % HP;
    const float* As_n = As + ni*81;
    const int*   ip   = Ip + ni*9;
    float scx=1.f, shx=0.f, scy=1.f, shy=0.f;
    if (AFFINE){
      scx = scale[2*c2];   shx = shift[2*c2];
      scy = scale[2*c2+1]; shy = shift[2*c2+1];
    }
    float fx[9], fy[9];
    #pragma unroll
    for (int k = 0; k < 9; k++){
      unsigned v = *(const unsigned*)(in + ((size_t)ip[k]*16 + b)*CINP + 2*c2);
      float x0 = bflo(v), y0 = bfhi(v);
      if (AFFINE){
        x0 = fmaxf(fmaf(x0, scx, shx), 0.f);
        y0 = fmaxf(fmaf(y0, scy, shy), 0.f);
      }
      fx[k] = x0; fy[k] = y0;
    }
    unsigned short e[18];
    #pragma unroll
    for (int t = 0; t < 9; t++){
      float s0 = 0.f, s1 = 0.f;
      #pragma unroll
      for (int k = 0; k < 9; k++){
        float a = As_n[k*9 + t];
        s0 = fmaf(fx[k], a, s0);
        s1 = fmaf(fy[k], a, s1);
      }
      e[t] = f2bf(s0); e[9+t] = f2bf(s1);
    }
    unsigned* dst = (unsigned*)(Tb + (ni*16 + b)*KROW + 18*c2);
    #pragma unroll
    for (int j = 0; j < 9; j++) dst[j] = (unsigned)e[2*j] | ((unsigned)e[2*j+1] << 16);
  }
  __syncthreads();

  int w = tid >> 6, l = tid & 63, lr = l & 15, lg = l >> 4;
  float smr[4] = {0,0,0,0}, sqr[4] = {0,0,0,0};
  int oBase = 0;
  for (int wi = w; wi < NPB*OT; wi += 4){
    int ni = wi / OT, ot = wi % OT;
    oBase = 16*ot + 4*lg;
    f32x4 acc;
    #pragma unroll
    for (int r = 0; r < 4; r++) acc[r] = bias[oBase + r];
    const short8v* ap = (const short8v*)(Wb + (size_t)(16*ot + lr)*KW) + lg;
    const short8v* bp = (const short8v*)(Tb + (ni*16 + lr)*KROW) + lg;
    #pragma unroll
    for (int kk = 0; kk < CHUNKS; kk++)
      acc = __builtin_amdgcn_mfma_f32_16x16x32_bf16(ap[kk*4], bp[kk*4], acc, 0, 0, 0);
    ushort4 o4;
    o4.x = f2bf(acc[0]); o4.y = f2bf(acc[1]); o4.z = f2bf(acc[2]); o4.w = f2bf(acc[3]);
    *(ushort4*)(out + ((size_t)(n0 + ni)*16 + lr)*COUT + oBase) = o4;
    #pragma unroll
    for (int r = 0; r < 4; r++){
      smr[r] += acc[r];
      sqr[r] = fmaf(acc[r], acc[r], sqr[r]);
    }
  }
  #pragma unroll
  for (int m = 1; m < 16; m <<= 1){
    #pragma unroll
    for (int r = 0; r < 4; r++){
      smr[r] += __shfl_xor(smr[r], m);
      sqr[r] += __shfl_xor(sqr[r], m);
    }
  }
  if (lr == 0){
    #pragma unroll
    for (int r = 0; r < 4; r++){
      Sw[w*COUT + oBase + r] = smr[r];
      Sq[w*COUT + oBase + r] = sqr[r];
    }
  }
  __syncthreads();
  for (int o = tid; o < COUT; o += 256){
    float sm = Sw[o] + Sw[COUT + o] + Sw[2*COUT + o] + Sw[3*COUT + o];
    float sq = Sq[o] + Sq[COUT + o] + Sq[2*COUT + o] + Sq[3*COUT + o];
    gpart[(size_t)blockIdx.x * 2*COUT + o] = sm;
    gpart[(size_t)blockIdx.x * 2*COUT + COUT + o] = sq;
  }
}

// ======== conv2/3: wave-per-point, ZERO taps staging ========
// Key insight: for mfma_16x16x32, lane (lr,lg)'s B-fragment at step kk is
// taps[b=lr][t=kk][c=lg*8+j] — exactly what thread (b=lr, cg=lg) computes.
// So taps never leave registers: gather -> tv (18 named f32x4) -> pack ->
// 9 named short8v fragments -> MFMA. No Tb, no bank conflicts, 2KB LDS.
template<int COUT>
__global__ __launch_bounds__(256, 2) void conv_wave_kernel(
    const unsigned short* __restrict__ in, const int* __restrict__ idx,
    const float* __restrict__ Abuf, const unsigned short* __restrict__ Wb,
    const float* __restrict__ bias,
    const float* __restrict__ scale, const float* __restrict__ shift,
    unsigned short* __restrict__ out, float* __restrict__ gpart)
{
  constexpr int NPB = 4;               // waves per block, 1 point per wave
  constexpr int OT  = COUT / 16;
  constexpr int USZ = 128;             // per-wave union: A(108 fl) / stats(2*COUT)

  __shared__ alignas(16) float U[NPB * USZ];   // 2,048 B total

  int tid = threadIdx.x;
  int w = tid >> 6, l = tid & 63;
  int n0 = blockIdx.x * NPB;
  int nws = __builtin_amdgcn_readfirstlane(n0 + w);

  // --- issue A global loads (cooperative per-lane, 81 floats/wave) ---
  const float* Ap = Abuf + (size_t)nws * 81;
  float a0 = Ap[l];
  float a1 = (l < 17) ? Ap[64 + l] : 0.f;

  // --- knn row (uniform address -> s_loads) ---
  int ip[9];
  {
    const int* ipr = idx + nws * 9;
    #pragma unroll
    for (int k = 0; k < 9; k++) ip[k] = ipr[k];
  }

  // --- issue ALL 9 gathers (1KB/row, coalesced); keep in flight together ---
  int b = l & 15, cg = l >> 4;
  const unsigned short* gbase = in + b*32 + cg*8;
  uint4 rv0 = *(const uint4*)(gbase + (size_t)ip[0]*512);
  uint4 rv1 = *(const uint4*)(gbase + (size_t)ip[1]*512);
  uint4 rv2 = *(const uint4*)(gbase + (size_t)ip[2]*512);
  uint4 rv3 = *(const uint4*)(gbase + (size_t)ip[3]*512);
  uint4 rv4 = *(const uint4*)(gbase + (size_t)ip[4]*512);
  uint4 rv5 = *(const uint4*)(gbase + (size_t)ip[5]*512);
  uint4 rv6 = *(const uint4*)(gbase + (size_t)ip[6]*512);
  uint4 rv7 = *(const uint4*)(gbase + (size_t)ip[7]*512);
  uint4 rv8 = *(const uint4*)(gbase + (size_t)ip[8]*512);
  float4 scLf = *(const float4*)(scale + cg*8);
  float4 scHf = *(const float4*)(scale + cg*8 + 4);
  float4 shLf = *(const float4*)(shift + cg*8);
  float4 shHf = *(const float4*)(shift + cg*8 + 4);
  __builtin_amdgcn_sched_barrier(0);

  // --- park A in the per-wave LDS slot (wave-local broadcast source) ---
  float* Aw = U + w * USZ;
  {
    int k = l / 9, t = l - k*9;
    Aw[k*12 + t] = a0;
    if (l < 17){
      int j = l + 64;
      int k2 = j / 9, t2 = j - k2*9;
      Aw[k2*12 + t2] = a1;
    }
  }

  f32x4 scL; scL[0]=scLf.x; scL[1]=scLf.y; scL[2]=scLf.z; scL[3]=scLf.w;
  f32x4 shL; shL[0]=shLf.x; shL[1]=shLf.y; shL[2]=shLf.z; shL[3]=shLf.w;
  f32x4 scH; scH[0]=scHf.x; scH[1]=scHf.y; scH[2]=scHf.z; scH[3]=scHf.w;
  f32x4 shH; shH[0]=shHf.x; shH[1]=shHf.y; shH[2]=shHf.z; shH[3]=shHf.w;

  // --- taps: 18 named accumulators (tL_t = ch cg*8..+3, tH_t = +4..+7) ---
  f32x4 tL0={0,0,0,0},tL1={0,0,0,0},tL2={0,0,0,0},tL3={0,0,0,0},tL4={0,0,0,0},
        tL5={0,0,0,0},tL6={0,0,0,0},tL7={0,0,0,0},tL8={0,0,0,0};
  f32x4 tH0={0,0,0,0},tH1={0,0,0,0},tH2={0,0,0,0},tH3={0,0,0,0},tH4={0,0,0,0},
        tH5={0,0,0,0},tH6={0,0,0,0},tH7={0,0,0,0},tH8={0,0,0,0};

#define KSTEP(RV, K) { \
    f32x4 fL_, fH_; \
    fL_[0]=bflo(RV.x); fL_[1]=bfhi(RV.x); fL_[2]=bflo(RV.y); fL_[3]=bfhi(RV.y); \
    fH_[0]=bflo(RV.z); fH_[1]=bfhi(RV.z); fH_[2]=bflo(RV.w); fH_[3]=bfhi(RV.w); \
    fL_ = fL_ * scL + shL; fH_ = fH_ * scH + shH; \
    fL_[0]=fmaxf(fL_[0],0.f); fL_[1]=fmaxf(fL_[1],0.f); \
    fL_[2]=fmaxf(fL_[2],0.f); fL_[3]=fmaxf(fL_[3],0.f); \
    fH_[0]=fmaxf(fH_[0],0.f); fH_[1]=fmaxf(fH_[1],0.f); \
    fH_[2]=fmaxf(fH_[2],0.f); fH_[3]=fmaxf(fH_[3],0.f); \
    f32x4 a03_ = *(const f32x4*)(Aw + (K)*12); \
    f32x4 a47_ = *(const f32x4*)(Aw + (K)*12 + 4); \
    float a8_ = Aw[(K)*12 + 8]; \
    tL0 += fL_ * a03_[0]; tH0 += fH_ * a03_[0]; \
    tL1 += fL_ * a03_[1]; tH1 += fH_ * a03_[1]; \
    tL2 += fL_ * a03_[2]; tH2 += fH_ * a03_[2]; \
    tL3 += fL_ * a03_[3]; tH3 += fH_ * a03_[3]; \
    tL4 += fL_ * a47_[0]; tH4 += fH_ * a47_[0]; \
    tL5 += fL_ * a47_[1]; tH5 += fH_ * a47_[1]; \
    tL6 += fL_ * a47_[2]; tH6 += fH_ * a47_[2]; \
    tL7 += fL_ * a47_[3]; tH7 += fH_ * a47_[3]; \
    tL8 += fL_ * a8_;     tH8 += fH_ * a8_; }

  KSTEP(rv0,0) KSTEP(rv1,1) KSTEP(rv2,2) KSTEP(rv3,3) KSTEP(rv4,4)
  KSTEP(rv5,5) KSTEP(rv6,6) KSTEP(rv7,7) KSTEP(rv8,8)
#undef KSTEP

  // --- pack taps -> 9 named B-fragments (bf16, 4 VGPRs each) ---
  short8v fr0 = pack8(tL0, tH0);
  short8v fr1 = pack8(tL1, tH1);
  short8v fr2 = pack8(tL2, tH2);
  short8v fr3 = pack8(tL3, tH3);
  short8v fr4 = pack8(tL4, tH4);
  short8v fr5 = pack8(tL5, tH5);
  short8v fr6 = pack8(tL6, tH6);
  short8v fr7 = pack8(tL7, tH7);
  short8v fr8 = pack8(tL8, tH8);

  // --- MFMA: D(16x16) = W(16x288) . taps(288x16), B straight from regs ---
  f32x4 sm0={0,0,0,0}, sm1={0,0,0,0}, sm2={0,0,0,0}, sm3={0,0,0,0};
  f32x4 sq0={0,0,0,0}, sq1={0,0,0,0}, sq2={0,0,0,0}, sq3={0,0,0,0};
  #pragma unroll
  for (int ot = 0; ot < OT; ot++){
    int oBase = 16*ot + 4*cg;
    f32x4 a3;
    a3[0]=bias[oBase]; a3[1]=bias[oBase+1]; a3[2]=bias[oBase+2]; a3[3]=bias[oBase+3];
    const short8v* ap = (const short8v*)(Wb + (size_t)(16*ot + b)*288) + cg;
    a3 = __builtin_amdgcn_mfma_f32_16x16x32_bf16(ap[0],  fr0, a3, 0, 0, 0);
    a3 = __builtin_amdgcn_mfma_f32_16x16x32_bf16(ap[4],  fr1, a3, 0, 0, 0);
    a3 = __builtin_amdgcn_mfma_f32_16x16x32_bf16(ap[8],  fr2, a3, 0, 0, 0);
    a3 = __builtin_amdgcn_mfma_f32_16x16x32_bf16(ap[12], fr3, a3, 0, 0, 0);
    a3 = __builtin_amdgcn_mfma_f32_16x16x32_bf16(ap[16], fr4, a3, 0, 0, 0);
    a3 = __builtin_amdgcn_mfma_f32_16x16x32_bf16(ap[20], fr5, a3, 0, 0, 0);
    a3 = __builtin_amdgcn_mfma_f32_16x16x32_bf16(ap[24], fr6, a3, 0, 0, 0);
    a3 = __builtin_amdgcn_mfma_f32_16x16x32_bf16(ap[28], fr7, a3, 0, 0, 0);
    a3 = __builtin_amdgcn_mfma_f32_16x16x32_bf16(ap[32], fr8, a3, 0, 0, 0);
    ushort4 o4;
    o4.x = f2bf(a3[0]); o4.y = f2bf(a3[1]); o4.z = f2bf(a3[2]); o4.w = f2bf(a3[3]);
    *(ushort4*)(out + ((size_t)nws*16 + b)*COUT + oBase) = o4;
    if (ot==0){ sm0 += a3; sq0 += a3*a3; }
    else if (ot==1){ sm1 += a3; sq1 += a3*a3; }
    else if (ot==2){ sm2 += a3; sq2 += a3*a3; }
    else { sm3 += a3; sq3 += a3*a3; }
  }

  // --- stats: shuffle-reduce over b lanes; U slot (A dead) holds partials ---
  #pragma unroll
  for (int ot = 0; ot < OT; ot++){
    f32x4 s = (ot==0) ? sm0 : ((ot==1) ? sm1 : ((ot==2) ? sm2 : sm3));
    f32x4 q = (ot==0) ? sq0 : ((ot==1) ? sq1 : ((ot==2) ? sq2 : sq3));
    #pragma unroll
    for (int m = 1; m < 16; m <<= 1){
      #pragma unroll
      for (int r = 0; r < 4; r++){
        s[r] += __shfl_xor(s[r], m);
        q[r] += __shfl_xor(q[r], m);
      }
    }
    if (b == 0){
      int oBase = 16*ot + 4*cg;
      #pragma unroll
      for (int r = 0; r < 4; r++){
        U[w*USZ + oBase + r]        = s[r];
        U[w*USZ + COUT + oBase + r] = q[r];
      }
    }
  }
  __syncthreads();
  for (int o = tid; o < COUT; o += 256){
    float smv = U[o] + U[USZ + o] + U[2*USZ + o] + U[3*USZ + o];
    float sqv = U[COUT + o] + U[USZ + COUT + o] + U[2*USZ + COUT + o] + U[3*USZ + COUT + o];
    gpart[(size_t)blockIdx.x * 2*COUT + o] = smv;
    gpart[(size_t)blockIdx.x * 2*COUT + COUT + o] = sqv;
  }
}

// ---------------- finalize BN ----------------
__global__ __launch_bounds__(256) void bn_finalize_kernel(
    const float* __restrict__ gpart, int NB, int C,
    const float* __restrict__ g, const float* __restrict__ bb,
    float* __restrict__ sc, float* __restrict__ sh, float invN)
{
  int c = blockIdx.x;
  float sm = 0.f, sq = 0.f;
  for (int i = threadIdx.x; i < NB; i += 256){
    sm += gpart[(size_t)i*2*C + c];
    sq += gpart[(size_t)i*2*C + C + c];
  }
  #pragma unroll
  for (int off = 32; off > 0; off >>= 1){
    sm += __shfl_down(sm, off);
    sq += __shfl_down(sq, off);
  }
  __shared__ float rs[8];
  int wd = threadIdx.x >> 6, ln = threadIdx.x & 63;
  if (ln == 0){ rs[wd] = sm; rs[4+wd] = sq; }
  __syncthreads();
  if (threadIdx.x == 0){
    float S = rs[0]+rs[1]+rs[2]+rs[3], Q = rs[4]+rs[5]+rs[6]+rs[7];
    float mean = S * invN;
    float var  = fmaxf(Q * invN - mean*mean, 0.f);
    float s = g[c] * rsqrtf(var + 1e-5f);
    sc[c] = s;
    sh[c] = bb[c] - mean * s;
  }
}

// ------------- BN3 + relu + max-pool + write (16,64,N3) f32 -------------
__global__ __launch_bounds__(256) void pool_kernel(
    const unsigned short* __restrict__ h3, const int* __restrict__ pidx,
    const float* __restrict__ sc, const float* __restrict__ sh,
    float* __restrict__ out)
{
  __shared__ float P[16][1024];
  int m0 = blockIdx.x * 16;
  int tid = threadIdx.x;
  for (int mi = 0; mi < 16; mi++){
    int m = m0 + mi;
    int p0 = pidx[m*4+0], p1 = pidx[m*4+1], p2 = pidx[m*4+2], p3 = pidx[m*4+3];
    #pragma unroll
    for (int q = 0; q < 4; q++){
      int bo = tid + q*256;
      int o = bo & 63;
      float s = sc[o], h = sh[o];
      float v0 = fmaf(bf2f(h3[(size_t)p0*1024 + bo]), s, h);
      float v1 = fmaf(bf2f(h3[(size_t)p1*1024 + bo]), s, h);
      float v2 = fmaf(bf2f(h3[(size_t)p2*1024 + bo]), s, h);
      float v3 = fmaf(bf2f(h3[(size_t)p3*1024 + bo]), s, h);
      P[mi][bo] = fmaxf(fmaxf(fmaxf(v0,v1), fmaxf(v2,v3)), 0.f);
    }
  }
  __syncthreads();
  #pragma unroll
  for (int w = 0; w < 4; w++){
    int r = tid + w*256;
    float* dst = out + (size_t)r*N3C + m0;
    #pragma unroll
    for (int mi = 0; mi < 16; mi++) dst[mi] = P[mi][r];
  }
}

// ---------------- launch ----------------
extern "C" void kernel_launch(void* const* d_in, const int* in_sizes, int n_in,
                              void* d_out, int out_size, void* d_ws, size_t ws_size,
                              hipStream_t stream)
{
  const float* x    = (const float*)d_in[0];
  const float* l1   = (const float*)d_in[1];
  const float* l2   = (const float*)d_in[2];
  const int* knn1   = (const int*)d_in[4];
  const int* knn2   = (const int*)d_in[5];
  const int* knn3   = (const int*)d_in[6];
  const int* pidx   = (const int*)d_in[7];

  const float* c1_w1 = (const float*)d_in[8];
  const float* c1_b1 = (const float*)d_in[9];
  const float* c1_w2 = (const float*)d_in[10];
  const float* c1_b2 = (const float*)d_in[11];
  const float* c1_k  = (const float*)d_in[12];
  const float* c1_bs = (const float*)d_in[13];
  const float* c2_w1 = (const float*)d_in[14];
  const float* c2_b1 = (const float*)d_in[15];
  const float* c2_w2 = (const float*)d_in[16];
  const float* c2_b2 = (const float*)d_in[17];
  const float* c2_k  = (const float*)d_in[18];
  const float* c2_bs = (const float*)d_in[19];
  const float* c3_w1 = (const float*)d_in[20];
  const float* c3_b1 = (const float*)d_in[21];
  const float* c3_w2 = (const float*)d_in[22];
  const float* c3_b2 = (const float*)d_in[23];
  const float* c3_k  = (const float*)d_in[24];
  const float* c3_bs = (const float*)d_in[25];
  const float* bn1_g = (const float*)d_in[26];
  const float* bn1_b = (const float*)d_in[27];
  const float* bn2_g = (const float*)d_in[28];
  const float* bn2_b = (const float*)d_in[29];
  const float* bn3_g = (const float*)d_in[30];
  const float* bn3_b = (const float*)d_in[31];

  char* ws = (char*)d_ws;
  unsigned short* xTb = (unsigned short*)(ws + 0);
  unsigned short* h1  = (unsigned short*)(ws + 6422528);
  unsigned short* h2  = (unsigned short*)(ws + 19267584);
  unsigned short* h3  = (unsigned short*)(ws + 32112640);
  float* Abuf         = (float*)(ws + 57802752);
  float* gpart        = (float*)(ws + 61867008);
  unsigned short* wb1 = (unsigned short*)(ws + 65078272);
  unsigned short* wb2 = (unsigned short*)(ws + 65081344);
  unsigned short* wb3 = (unsigned short*)(ws + 65099776);
  float* sc1 = (float*)(ws + 65137664); float* sh1 = sc1 + 32;
  float* sc2 = sh1 + 32;                float* sh2 = sc2 + 32;
  float* sc3 = sh2 + 32;                float* sh3 = sc3 + 64;

  const float invN = 1.0f / (float)(N2C * 16);
  const int ablocks = (N2C * 9 + 255) / 256;

  transpose_x_kernel<<<N1C/64, 256, 0, stream>>>(x, xTb);
  wcvt_kernel<<<(32*32 + 255)/256, 256, 0, stream>>>(c1_k, wb1, 32*32, 27, 32, 0);
  wcvt_kernel<<<(32*288 + 255)/256, 256, 0, stream>>>(c2_k, wb2, 32*288, 288, 288, 1);
  wcvt_kernel<<<(64*288 + 255)/256, 256, 0, stream>>>(c3_k, wb3, 64*288, 288, 288, 1);

  // conv1
  compute_A_kernel<<<ablocks, 256, 0, stream>>>(l1, l2, knn1, c1_w1, c1_b1, c1_w2, c1_b2, Abuf);
  conv_mfma_kernel<3, 4, 32, 8, false><<<N2C/8, 256, 0, stream>>>(
      xTb, knn1, Abuf, wb1, c1_bs, nullptr, nullptr, h1, gpart);
  bn_finalize_kernel<<<32, 256, 0, stream>>>(gpart, N2C/8, 32, bn1_g, bn1_b, sc1, sh1, invN);

  // conv2
  compute_A_kernel<<<ablocks, 256, 0, stream>>>(l2, l2, knn2, c2_w1, c2_b1, c2_w2, c2_b2, Abuf);
  conv_wave_kernel<32><<<N2C/4, 256, 0, stream>>>(
      h1, knn2, Abuf, wb2, c2_bs, sc1, sh1, h2, gpart);
  bn_finalize_kernel<<<32, 256, 0, stream>>>(gpart, N2C/4, 32, bn2_g, bn2_b, sc2, sh2, invN);

  // conv3
  compute_A_kernel<<<ablocks, 256, 0, stream>>>(l2, l2, knn3, c3_w1, c3_b1, c3_w2, c3_b2, Abuf);
  conv_wave_kernel<64><<<N2C/4, 256, 0, stream>>>(
      h2, knn3, Abuf, wb3, c3_bs, sc2, sh2, h3, gpart);
  bn_finalize_kernel<<<64, 256, 0, stream>>>(gpart, N2C/4, 64, bn3_g, bn3_b, sc3, sh3, invN);

  pool_kernel<<<N3C/16, 256, 0, stream>>>(h3, pidx, sc3, sh3, (float*)d_out);
}

// Round 14
// 142.537 us; speedup vs baseline: 1.4935x; 1.2002x over previous
//
#include <hip/hip_runtime.h>
#include <hip/hip_bf16.h>
#include <cfloat>

#define N1C 50176
#define N2C 12544
#define N3C 3136

typedef __attribute__((ext_vector_type(8))) short short8v;
typedef __attribute__((ext_vector_type(4))) float f32x4;

static __device__ __forceinline__ unsigned short f2bf(float f){
  __hip_bfloat16 h = __float2bfloat16(f);
  return *reinterpret_cast<unsigned short*>(&h);
}
static __device__ __forceinline__ float bflo(unsigned v){
  return __uint_as_float(v << 16);
}
static __device__ __forceinline__ float bfhi(unsigned v){
  return __uint_as_float(v & 0xFFFF0000u);
}
static __device__ __forceinline__ float bf2f(unsigned short u){
  return __uint_as_float(((unsigned)u) << 16);
}
static __device__ __forceinline__ unsigned pk2(float a, float b){
  return (unsigned)f2bf(a) | ((unsigned)f2bf(b) << 16);
}
static __device__ __forceinline__ short8v pack8(f32x4 L, f32x4 H){
  short8v r;
  r[0]=(short)f2bf(L[0]); r[1]=(short)f2bf(L[1]); r[2]=(short)f2bf(L[2]); r[3]=(short)f2bf(L[3]);
  r[4]=(short)f2bf(H[0]); r[5]=(short)f2bf(H[1]); r[6]=(short)f2bf(H[2]); r[7]=(short)f2bf(H[3]);
  return r;
}

// ---------------- transpose x: (16,3,N1) f32 -> xTb (N1, 16, 4) bf16 ----
__global__ __launch_bounds__(256) void transpose_x_kernel(
    const float* __restrict__ x, unsigned short* __restrict__ xTb)
{
  __shared__ float tile[48][65];
  int n0 = blockIdx.x * 64;
  int tid = threadIdx.x;
  int i = tid & 63;
  for (int rr = tid >> 6; rr < 48; rr += 4)
    tile[rr][i] = x[(size_t)rr * N1C + n0 + i];
  __syncthreads();
  for (int j = tid; j < 64*64; j += 256){
    int ii = j >> 6, bc = j & 63, b = bc >> 2, c = bc & 3;
    float v = (c < 3) ? tile[b*3 + c][ii] : 0.f;
    xTb[(size_t)n0 * 64 + j] = f2bf(v);
  }
}

// ---------------- A[n,k,t] = (relu(off @ w1 + b1) @ w2 + b2) ----------------
__global__ __launch_bounds__(256) void compute_A_kernel(
    const float* __restrict__ pos_in, const float* __restrict__ pos_out,
    const int* __restrict__ idx,
    const float* __restrict__ w1, const float* __restrict__ b1,
    const float* __restrict__ w2, const float* __restrict__ b2,
    float* __restrict__ Abuf)
{
  int g = blockIdx.x * 256 + threadIdx.x;
  if (g >= N2C * 9) return;
  int n = g / 9;
  int p = idx[g];
  float o0 = pos_in[2*p]   - pos_out[2*n];
  float o1 = pos_in[2*p+1] - pos_out[2*n+1];
  float A[9];
  #pragma unroll
  for (int t = 0; t < 9; t++) A[t] = b2[t];
  #pragma unroll
  for (int j = 0; j < 16; j++){
    float h = fmaxf(fmaf(o0, w1[j], fmaf(o1, w1[16+j], b1[j])), 0.f);
    #pragma unroll
    for (int t = 0; t < 9; t++) A[t] = fmaf(h, w2[j*9 + t], A[t]);
  }
  #pragma unroll
  for (int t = 0; t < 9; t++) Abuf[(size_t)g*9 + t] = A[t];
}

// ------ W (o,c,t) f32 -> Wb bf16. mode0: Wb[o][k=c*9+t] pad to KW.
// ------ mode1: Wb[o][k'=t*32+c] (t-major permutation, K=KW=288).
__global__ __launch_bounds__(256) void wcvt_kernel(
    const float* __restrict__ W, unsigned short* __restrict__ Wb,
    int total, int K, int KW, int mode)
{
  int i = blockIdx.x * 256 + threadIdx.x;
  if (i >= total) return;
  int o = i / KW, r = i % KW;
  float v;
  if (mode == 0){
    v = (r < K) ? W[o*K + r] : 0.f;
  } else {
    int t = r >> 5, c = r & 31;          // r = t*32 + c
    v = W[o*288 + c*9 + t];
  }
  Wb[i] = f2bf(v);
}

// ======== conv1 path (small CIN), linear k-layout ========
template<int CIN, int CINP, int COUT, int NPB, bool AFFINE>
__global__ __launch_bounds__(256) void conv_mfma_kernel(
    const unsigned short* __restrict__ in, const int* __restrict__ idx,
    const float* __restrict__ Abuf, const unsigned short* __restrict__ Wb,
    const float* __restrict__ bias,
    const float* __restrict__ scale, const float* __restrict__ shift,
    unsigned short* __restrict__ out, float* __restrict__ gpart)
{
  constexpr int K    = CIN * 9;
  constexpr int KW   = (K < 32) ? 32 : K;
  constexpr int KROW = (K < 32) ? 48 : 296;
  constexpr int CHUNKS = KW / 32;
  constexpr int OT   = COUT / 16;
  constexpr int HP   = CINP / 2;
  constexpr int PPT  = 16 * HP;

  __shared__ alignas(16) unsigned short Tb[NPB * 16 * KROW];
  __shared__ float As[NPB * 81];
  __shared__ int   Ip[NPB * 9];
  __shared__ float Sw[4 * COUT];
  __shared__ float Sq[4 * COUT];

  int n0 = blockIdx.x * NPB;
  int tid = threadIdx.x;
  for (int i = tid; i < NPB*81; i += 256) As[i] = Abuf[(size_t)n0*81 + i];
  if (tid < NPB*9) Ip[tid] = idx[n0*9 + tid];
  for (int i = tid; i < 4*COUT; i += 256){ Sw[i] = 0.f; Sq[i] = 0.f; }
  if (K < 32){
    for (int i = tid; i < NPB*16*KROW/2; i += 256) ((unsigned*)Tb)[i] = 0u;
  }
  __syncthreads();

  for (int u = tid; u < NPB*PPT; u += 256){
    int ni = u / PPT, loc = u % PPT;
    int b = loc / HP, c2 = loc % HP;
    const float* As_n = As + ni*81;
    const int*   ip   = Ip + ni*9;
    float scx=1.f, shx=0.f, scy=1.f, shy=0.f;
    if (AFFINE){
      scx = scale[2*c2];   shx = shift[2*c2];
      scy = scale[2*c2+1]; shy = shift[2*c2+1];
    }
    float fx[9], fy[9];
    #pragma unroll
    for (int k = 0; k < 9; k++){
      unsigned v = *(const unsigned*)(in + ((size_t)ip[k]*16 + b)*CINP + 2*c2);
      float x0 = bflo(v), y0 = bfhi(v);
      if (AFFINE){
        x0 = fmaxf(fmaf(x0, scx, shx), 0.f);
        y0 = fmaxf(fmaf(y0, scy, shy), 0.f);
      }
      fx[k] = x0; fy[k] = y0;
    }
    unsigned short e[18];
    #pragma unroll
    for (int t = 0; t < 9; t++){
      float s0 = 0.f, s1 = 0.f;
      #pragma unroll
      for (int k = 0; k < 9; k++){
        float a = As_n[k*9 + t];
        s0 = fmaf(fx[k], a, s0);
        s1 = fmaf(fy[k], a, s1);
      }
      e[t] = f2bf(s0); e[9+t] = f2bf(s1);
    }
    unsigned* dst = (unsigned*)(Tb + (ni*16 + b)*KROW + 18*c2);
    #pragma unroll
    for (int j = 0; j < 9; j++) dst[j] = (unsigned)e[2*j] | ((unsigned)e[2*j+1] << 16);
  }
  __syncthreads();

  int w = tid >> 6, l = tid & 63, lr = l & 15, lg = l >> 4;
  float smr[4] = {0,0,0,0}, sqr[4] = {0,0,0,0};
  int oBase = 0;
  for (int wi = w; wi < NPB*OT; wi += 4){
    int ni = wi / OT, ot = wi % OT;
    oBase = 16*ot + 4*lg;
    f32x4 acc;
    #pragma unroll
    for (int r = 0; r < 4; r++) acc[r] = bias[oBase + r];
    const short8v* ap = (const short8v*)(Wb + (size_t)(16*ot + lr)*KW) + lg;
    const short8v* bp = (const short8v*)(Tb + (ni*16 + lr)*KROW) + lg;
    #pragma unroll
    for (int kk = 0; kk < CHUNKS; kk++)
      acc = __builtin_amdgcn_mfma_f32_16x16x32_bf16(ap[kk*4], bp[kk*4], acc, 0, 0, 0);
    ushort4 o4;
    o4.x = f2bf(acc[0]); o4.y = f2bf(acc[1]); o4.z = f2bf(acc[2]); o4.w = f2bf(acc[3]);
    *(ushort4*)(out + ((size_t)(n0 + ni)*16 + lr)*COUT + oBase) = o4;
    #pragma unroll
    for (int r = 0; r < 4; r++){
      smr[r] += acc[r];
      sqr[r] = fmaf(acc[r], acc[r], sqr[r]);
    }
  }
  #pragma unroll
  for (int m = 1; m < 16; m <<= 1){
    #pragma unroll
    for (int r = 0; r < 4; r++){
      smr[r] += __shfl_xor(smr[r], m);
      sqr[r] += __shfl_xor(sqr[r], m);
    }
  }
  if (lr == 0){
    #pragma unroll
    for (int r = 0; r < 4; r++){
      Sw[w*COUT + oBase + r] = smr[r];
      Sq[w*COUT + oBase + r] = sqr[r];
    }
  }
  __syncthreads();
  for (int o = tid; o < COUT; o += 256){
    float sm = Sw[o] + Sw[COUT + o] + Sw[2*COUT + o] + Sw[3*COUT + o];
    float sq = Sq[o] + Sq[COUT + o] + Sq[2*COUT + o] + Sq[3*COUT + o];
    gpart[(size_t)blockIdx.x * 2*COUT + o] = sm;
    gpart[(size_t)blockIdx.x * 2*COUT + COUT + o] = sq;
  }
}

// ======== conv2/3: zero taps staging + W in LDS + 4 points/wave pipeline ====
// Per point: gather -> 18 named f32x4 taps -> pack to 9 B-frags -> MFMA vs
// LDS-resident W. Next point's gathers issued before MFMA (latency hidden).

#define PREFETCH(NWSN) { \
    const float* Ap_ = Abuf + (size_t)(NWSN)*81; \
    a0 = Ap_[l]; a1 = (l < 17) ? Ap_[64 + l] : 0.f; \
    const int* ipr_ = idx + (size_t)(NWSN)*9; \
    int i0_=ipr_[0], i1_=ipr_[1], i2_=ipr_[2], i3_=ipr_[3], i4_=ipr_[4], \
        i5_=ipr_[5], i6_=ipr_[6], i7_=ipr_[7], i8_=ipr_[8]; \
    rv0 = *(const uint4*)(gbase + (size_t)i0_*512); \
    rv1 = *(const uint4*)(gbase + (size_t)i1_*512); \
    rv2 = *(const uint4*)(gbase + (size_t)i2_*512); \
    rv3 = *(const uint4*)(gbase + (size_t)i3_*512); \
    rv4 = *(const uint4*)(gbase + (size_t)i4_*512); \
    rv5 = *(const uint4*)(gbase + (size_t)i5_*512); \
    rv6 = *(const uint4*)(gbase + (size_t)i6_*512); \
    rv7 = *(const uint4*)(gbase + (size_t)i7_*512); \
    rv8 = *(const uint4*)(gbase + (size_t)i8_*512); }

#define AWRITE { int k_ = l/9, t_ = l - k_*9; Aw[k_*12 + t_] = a0; \
    if (l < 17){ int j_ = l + 64; int k2_ = j_/9, t2_ = j_ - k2_*9; Aw[k2_*12 + t2_] = a1; } }

#define KSTEP(RV, K) { \
    f32x4 fL_, fH_; \
    fL_[0]=bflo(RV.x); fL_[1]=bfhi(RV.x); fL_[2]=bflo(RV.y); fL_[3]=bfhi(RV.y); \
    fH_[0]=bflo(RV.z); fH_[1]=bfhi(RV.z); fH_[2]=bflo(RV.w); fH_[3]=bfhi(RV.w); \
    fL_ = fL_ * scL + shL; fH_ = fH_ * scH + shH; \
    fL_[0]=fmaxf(fL_[0],0.f); fL_[1]=fmaxf(fL_[1],0.f); \
    fL_[2]=fmaxf(fL_[2],0.f); fL_[3]=fmaxf(fL_[3],0.f); \
    fH_[0]=fmaxf(fH_[0],0.f); fH_[1]=fmaxf(fH_[1],0.f); \
    fH_[2]=fmaxf(fH_[2],0.f); fH_[3]=fmaxf(fH_[3],0.f); \
    f32x4 a03_ = *(const f32x4*)(Aw + (K)*12); \
    f32x4 a47_ = *(const f32x4*)(Aw + (K)*12 + 4); \
    float a8_ = Aw[(K)*12 + 8]; \
    tL0 += fL_ * a03_[0]; tH0 += fH_ * a03_[0]; \
    tL1 += fL_ * a03_[1]; tH1 += fH_ * a03_[1]; \
    tL2 += fL_ * a03_[2]; tH2 += fH_ * a03_[2]; \
    tL3 += fL_ * a03_[3]; tH3 += fH_ * a03_[3]; \
    tL4 += fL_ * a47_[0]; tH4 += fH_ * a47_[0]; \
    tL5 += fL_ * a47_[1]; tH5 += fH_ * a47_[1]; \
    tL6 += fL_ * a47_[2]; tH6 += fH_ * a47_[2]; \
    tL7 += fL_ * a47_[3]; tH7 += fH_ * a47_[3]; \
    tL8 += fL_ * a8_;     tH8 += fH_ * a8_; }

#define TAPS_AND_PACK { \
    f32x4 tL0={0,0,0,0},tL1={0,0,0,0},tL2={0,0,0,0},tL3={0,0,0,0},tL4={0,0,0,0}, \
          tL5={0,0,0,0},tL6={0,0,0,0},tL7={0,0,0,0},tL8={0,0,0,0}; \
    f32x4 tH0={0,0,0,0},tH1={0,0,0,0},tH2={0,0,0,0},tH3={0,0,0,0},tH4={0,0,0,0}, \
          tH5={0,0,0,0},tH6={0,0,0,0},tH7={0,0,0,0},tH8={0,0,0,0}; \
    KSTEP(rv0,0) KSTEP(rv1,1) KSTEP(rv2,2) KSTEP(rv3,3) KSTEP(rv4,4) \
    KSTEP(rv5,5) KSTEP(rv6,6) KSTEP(rv7,7) KSTEP(rv8,8) \
    fr0 = pack8(tL0,tH0); fr1 = pack8(tL1,tH1); fr2 = pack8(tL2,tH2); \
    fr3 = pack8(tL3,tH3); fr4 = pack8(tL4,tH4); fr5 = pack8(tL5,tH5); \
    fr6 = pack8(tL6,tH6); fr7 = pack8(tL7,tH7); fr8 = pack8(tL8,tH8); }

#define MFMA_STATS(NWSC) { \
    _Pragma("unroll") \
    for (int ot = 0; ot < OT; ot++){ \
      int oBase = 16*ot + 4*cg; \
      f32x4 a3; \
      a3[0]=bias[oBase]; a3[1]=bias[oBase+1]; a3[2]=bias[oBase+2]; a3[3]=bias[oBase+3]; \
      const short8v* ap_ = (const short8v*)(Wl + (size_t)(16*ot + b)*WROW) + cg; \
      a3 = __builtin_amdgcn_mfma_f32_16x16x32_bf16(ap_[0],  fr0, a3, 0, 0, 0); \
      a3 = __builtin_amdgcn_mfma_f32_16x16x32_bf16(ap_[4],  fr1, a3, 0, 0, 0); \
      a3 = __builtin_amdgcn_mfma_f32_16x16x32_bf16(ap_[8],  fr2, a3, 0, 0, 0); \
      a3 = __builtin_amdgcn_mfma_f32_16x16x32_bf16(ap_[12], fr3, a3, 0, 0, 0); \
      a3 = __builtin_amdgcn_mfma_f32_16x16x32_bf16(ap_[16], fr4, a3, 0, 0, 0); \
      a3 = __builtin_amdgcn_mfma_f32_16x16x32_bf16(ap_[20], fr5, a3, 0, 0, 0); \
      a3 = __builtin_amdgcn_mfma_f32_16x16x32_bf16(ap_[24], fr6, a3, 0, 0, 0); \
      a3 = __builtin_amdgcn_mfma_f32_16x16x32_bf16(ap_[28], fr7, a3, 0, 0, 0); \
      a3 = __builtin_amdgcn_mfma_f32_16x16x32_bf16(ap_[32], fr8, a3, 0, 0, 0); \
      ushort4 o4_; \
      o4_.x = f2bf(a3[0]); o4_.y = f2bf(a3[1]); o4_.z = f2bf(a3[2]); o4_.w = f2bf(a3[3]); \
      *(ushort4*)(out + ((size_t)(NWSC)*16 + b)*COUT + oBase) = o4_; \
      if (ot==0){ sm0 += a3; sq0 += a3*a3; } \
      else if (ot==1){ sm1 += a3; sq1 += a3*a3; } \
      else if (ot==2){ sm2 += a3; sq2 += a3*a3; } \
      else { sm3 += a3; sq3 += a3*a3; } } }

template<int COUT>
__global__ __launch_bounds__(256, 2) void conv_wave_kernel(
    const unsigned short* __restrict__ in, const int* __restrict__ idx,
    const float* __restrict__ Abuf, const unsigned short* __restrict__ Wb,
    const float* __restrict__ bias,
    const float* __restrict__ scale, const float* __restrict__ shift,
    unsigned short* __restrict__ out, float* __restrict__ gpart)
{
  constexpr int NPB  = 4;              // waves per block
  constexpr int PPW  = 4;              // points per wave
  constexpr int OT   = COUT / 16;
  constexpr int WROW = 296;            // LDS W row stride (shorts) — 2-way banks
  constexpr int USZ  = 128;            // per-wave union: A(108) / stats(2*COUT)

  __shared__ alignas(16) unsigned short Wl[COUT * WROW]; // 18,944 / 37,888 B
  __shared__ alignas(16) float U[NPB * USZ];             //  2,048 B

  int tid = threadIdx.x;
  int w = tid >> 6, l = tid & 63;
  int base = blockIdx.x * (NPB*PPW) + w * PPW;
  int b = l & 15, cg = l >> 4;

  // --- cooperative W stage: COUT*36 uint4 chunks ---
  for (int j = tid; j < COUT*36; j += 256){
    int o = j / 36, c = j % 36;
    *(uint4*)(Wl + (size_t)o*WROW + c*8) = *(const uint4*)(Wb + (size_t)o*288 + c*8);
  }

  const unsigned short* gbase = in + b*32 + cg*8;
  float* Aw = U + w * USZ;

  float4 scLf = *(const float4*)(scale + cg*8);
  float4 scHf = *(const float4*)(scale + cg*8 + 4);
  float4 shLf = *(const float4*)(shift + cg*8);
  float4 shHf = *(const float4*)(shift + cg*8 + 4);
  f32x4 scL; scL[0]=scLf.x; scL[1]=scLf.y; scL[2]=scLf.z; scL[3]=scLf.w;
  f32x4 shL; shL[0]=shLf.x; shL[1]=shLf.y; shL[2]=shLf.z; shL[3]=shLf.w;
  f32x4 scH; scH[0]=scHf.x; scH[1]=scHf.y; scH[2]=scHf.z; scH[3]=scHf.w;
  f32x4 shH; shH[0]=shHf.x; shH[1]=shHf.y; shH[2]=shHf.z; shH[3]=shHf.w;

  __syncthreads();   // W + (first) A slot ready users

  f32x4 sm0={0,0,0,0}, sm1={0,0,0,0}, sm2={0,0,0,0}, sm3={0,0,0,0};
  f32x4 sq0={0,0,0,0}, sq1={0,0,0,0}, sq2={0,0,0,0}, sq3={0,0,0,0};
  uint4 rv0,rv1,rv2,rv3,rv4,rv5,rv6,rv7,rv8;
  short8v fr0,fr1,fr2,fr3,fr4,fr5,fr6,fr7,fr8;
  float a0, a1;

  // ---- prologue: point 0 loads ----
  int nws0 = __builtin_amdgcn_readfirstlane(base + 0);
  PREFETCH(nws0);
  AWRITE;

  // ---- p0: compute; prefetch p1 under MFMA ----
  TAPS_AND_PACK;
  int nws1 = __builtin_amdgcn_readfirstlane(base + 1);
  PREFETCH(nws1);
  __builtin_amdgcn_sched_barrier(0);
  MFMA_STATS(nws0);
  AWRITE;

  // ---- p1 ----
  TAPS_AND_PACK;
  int nws2 = __builtin_amdgcn_readfirstlane(base + 2);
  PREFETCH(nws2);
  __builtin_amdgcn_sched_barrier(0);
  MFMA_STATS(nws1);
  AWRITE;

  // ---- p2 ----
  TAPS_AND_PACK;
  int nws3 = __builtin_amdgcn_readfirstlane(base + 3);
  PREFETCH(nws3);
  __builtin_amdgcn_sched_barrier(0);
  MFMA_STATS(nws2);
  AWRITE;

  // ---- p3 (no prefetch) ----
  TAPS_AND_PACK;
  MFMA_STATS(nws3);

  // ---- stats: reduce over b lanes; U slot (A dead) holds partials ----
  #pragma unroll
  for (int ot = 0; ot < OT; ot++){
    f32x4 s = (ot==0) ? sm0 : ((ot==1) ? sm1 : ((ot==2) ? sm2 : sm3));
    f32x4 q = (ot==0) ? sq0 : ((ot==1) ? sq1 : ((ot==2) ? sq2 : sq3));
    #pragma unroll
    for (int m = 1; m < 16; m <<= 1){
      #pragma unroll
      for (int r = 0; r < 4; r++){
        s[r] += __shfl_xor(s[r], m);
        q[r] += __shfl_xor(q[r], m);
      }
    }
    if (b == 0){
      int oBase = 16*ot + 4*cg;
      #pragma unroll
      for (int r = 0; r < 4; r++){
        U[w*USZ + oBase + r]        = s[r];
        U[w*USZ + COUT + oBase + r] = q[r];
      }
    }
  }
  __syncthreads();
  for (int o = tid; o < COUT; o += 256){
    float smv = U[o] + U[USZ + o] + U[2*USZ + o] + U[3*USZ + o];
    float sqv = U[COUT + o] + U[USZ + COUT + o] + U[2*USZ + COUT + o] + U[3*USZ + COUT + o];
    gpart[(size_t)blockIdx.x * 2*COUT + o] = smv;
    gpart[(size_t)blockIdx.x * 2*COUT + COUT + o] = sqv;
  }
}

#undef PREFETCH
#undef AWRITE
#undef KSTEP
#undef TAPS_AND_PACK
#undef MFMA_STATS

// ---------------- finalize BN ----------------
__global__ __launch_bounds__(256) void bn_finalize_kernel(
    const float* __restrict__ gpart, int NB, int C,
    const float* __restrict__ g, const float* __restrict__ bb,
    float* __restrict__ sc, float* __restrict__ sh, float invN)
{
  int c = blockIdx.x;
  float sm = 0.f, sq = 0.f;
  for (int i = threadIdx.x; i < NB; i += 256){
    sm += gpart[(size_t)i*2*C + c];
    sq += gpart[(size_t)i*2*C + C + c];
  }
  #pragma unroll
  for (int off = 32; off > 0; off >>= 1){
    sm += __shfl_down(sm, off);
    sq += __shfl_down(sq, off);
  }
  __shared__ float rs[8];
  int wd = threadIdx.x >> 6, ln = threadIdx.x & 63;
  if (ln == 0){ rs[wd] = sm; rs[4+wd] = sq; }
  __syncthreads();
  if (threadIdx.x == 0){
    float S = rs[0]+rs[1]+rs[2]+rs[3], Q = rs[4]+rs[5]+rs[6]+rs[7];
    float mean = S * invN;
    float var  = fmaxf(Q * invN - mean*mean, 0.f);
    float s = g[c] * rsqrtf(var + 1e-5f);
    sc[c] = s;
    sh[c] = bb[c] - mean * s;
  }
}

// ------------- BN3 + relu + max-pool + write (16,64,N3) f32 -------------
__global__ __launch_bounds__(256) void pool_kernel(
    const unsigned short* __restrict__ h3, const int* __restrict__ pidx,
    const float* __restrict__ sc, const float* __restrict__ sh,
    float* __restrict__ out)
{
  __shared__ float P[16][1024];
  int m0 = blockIdx.x * 16;
  int tid = threadIdx.x;
  for (int mi = 0; mi < 16; mi++){
    int m = m0 + mi;
    int p0 = pidx[m*4+0], p1 = pidx[m*4+1], p2 = pidx[m*4+2], p3 = pidx[m*4+3];
    #pragma unroll
    for (int q = 0; q < 4; q++){
      int bo = tid + q*256;
      int o = bo & 63;
      float s = sc[o], h = sh[o];
      float v0 = fmaf(bf2f(h3[(size_t)p0*1024 + bo]), s, h);
      float v1 = fmaf(bf2f(h3[(size_t)p1*1024 + bo]), s, h);
      float v2 = fmaf(bf2f(h3[(size_t)p2*1024 + bo]), s, h);
      float v3 = fmaf(bf2f(h3[(size_t)p3*1024 + bo]), s, h);
      P[mi][bo] = fmaxf(fmaxf(fmaxf(v0,v1), fmaxf(v2,v3)), 0.f);
    }
  }
  __syncthreads();
  #pragma unroll
  for (int w = 0; w < 4; w++){
    int r = tid + w*256;
    float* dst = out + (size_t)r*N3C + m0;
    #pragma unroll
    for (int mi = 0; mi < 16; mi++) dst[mi] = P[mi][r];
  }
}

// ---------------- launch ----------------
extern "C" void kernel_launch(void* const* d_in, const int* in_sizes, int n_in,
                              void* d_out, int out_size, void* d_ws, size_t ws_size,
                              hipStream_t stream)
{
  const float* x    = (const float*)d_in[0];
  const float* l1   = (const float*)d_in[1];
  const float* l2   = (const float*)d_in[2];
  const int* knn1   = (const int*)d_in[4];
  const int* knn2   = (const int*)d_in[5];
  const int* knn3   = (const int*)d_in[6];
  const int* pidx   = (const int*)d_in[7];

  const float* c1_w1 = (const float*)d_in[8];
  const float* c1_b1 = (const float*)d_in[9];
  const float* c1_w2 = (const float*)d_in[10];
  const float* c1_b2 = (const float*)d_in[11];
  const float* c1_k  = (const float*)d_in[12];
  const float* c1_bs = (const float*)d_in[13];
  const float* c2_w1 = (const float*)d_in[14];
  const float* c2_b1 = (const float*)d_in[15];
  const float* c2_w2 = (const float*)d_in[16];
  const float* c2_b2 = (const float*)d_in[17];
  const float* c2_k  = (const float*)d_in[18];
  const float* c2_bs = (const float*)d_in[19];
  const float* c3_w1 = (const float*)d_in[20];
  const float* c3_b1 = (const float*)d_in[21];
  const float* c3_w2 = (const float*)d_in[22];
  const float* c3_b2 = (const float*)d_in[23];
  const float* c3_k  = (const float*)d_in[24];
  const float* c3_bs = (const float*)d_in[25];
  const float* bn1_g = (const float*)d_in[26];
  const float* bn1_b = (const float*)d_in[27];
  const float* bn2_g = (const float*)d_in[28];
  const float* bn2_b = (const float*)d_in[29];
  const float* bn3_g = (const float*)d_in[30];
  const float* bn3_b = (const float*)d_in[31];

  char* ws = (char*)d_ws;
  unsigned short* xTb = (unsigned short*)(ws + 0);
  unsigned short* h1  = (unsigned short*)(ws + 6422528);
  unsigned short* h2  = (unsigned short*)(ws + 19267584);
  unsigned short* h3  = (unsigned short*)(ws + 32112640);
  float* Abuf         = (float*)(ws + 57802752);
  float* gpart        = (float*)(ws + 61867008);
  unsigned short* wb1 = (unsigned short*)(ws + 65078272);
  unsigned short* wb2 = (unsigned short*)(ws + 65081344);
  unsigned short* wb3 = (unsigned short*)(ws + 65099776);
  float* sc1 = (float*)(ws + 65137664); float* sh1 = sc1 + 32;
  float* sc2 = sh1 + 32;                float* sh2 = sc2 + 32;
  float* sc3 = sh2 + 32;                float* sh3 = sc3 + 64;

  const float invN = 1.0f / (float)(N2C * 16);
  const int ablocks = (N2C * 9 + 255) / 256;
  const int cwblocks = N2C / 16;   // 784

  transpose_x_kernel<<<N1C/64, 256, 0, stream>>>(x, xTb);
  wcvt_kernel<<<(32*32 + 255)/256, 256, 0, stream>>>(c1_k, wb1, 32*32, 27, 32, 0);
  wcvt_kernel<<<(32*288 + 255)/256, 256, 0, stream>>>(c2_k, wb2, 32*288, 288, 288, 1);
  wcvt_kernel<<<(64*288 + 255)/256, 256, 0, stream>>>(c3_k, wb3, 64*288, 288, 288, 1);

  // conv1
  compute_A_kernel<<<ablocks, 256, 0, stream>>>(l1, l2, knn1, c1_w1, c1_b1, c1_w2, c1_b2, Abuf);
  conv_mfma_kernel<3, 4, 32, 8, false><<<N2C/8, 256, 0, stream>>>(
      xTb, knn1, Abuf, wb1, c1_bs, nullptr, nullptr, h1, gpart);
  bn_finalize_kernel<<<32, 256, 0, stream>>>(gpart, N2C/8, 32, bn1_g, bn1_b, sc1, sh1, invN);

  // conv2
  compute_A_kernel<<<ablocks, 256, 0, stream>>>(l2, l2, knn2, c2_w1, c2_b1, c2_w2, c2_b2, Abuf);
  conv_wave_kernel<32><<<cwblocks, 256, 0, stream>>>(
      h1, knn2, Abuf, wb2, c2_bs, sc1, sh1, h2, gpart);
  bn_finalize_kernel<<<32, 256, 0, stream>>>(gpart, cwblocks, 32, bn2_g, bn2_b, sc2, sh2, invN);

  // conv3
  compute_A_kernel<<<ablocks, 256, 0, stream>>>(l2, l2, knn3, c3_w1, c3_b1, c3_w2, c3_b2, Abuf);
  conv_wave_kernel<64><<<cwblocks, 256, 0, stream>>>(
      h2, knn3, Abuf, wb3, c3_bs, sc2, sh2, h3, gpart);
  bn_finalize_kernel<<<64, 256, 0, stream>>>(gpart, cwblocks, 64, bn3_g, bn3_b, sc3, sh3, invN);

  pool_kernel<<<N3C/16, 256, 0, stream>>>(h3, pidx, sc3, sh3, (float*)d_out);
}

// Round 15
// 142.404 us; speedup vs baseline: 1.4949x; 1.0009x over previous
//
#include <hip/hip_runtime.h>
#include <hip/hip_bf16.h>
#include <cfloat>

#define N1C 50176
#define N2C 12544
#define N3C 3136

typedef __attribute__((ext_vector_type(8))) short short8v;
typedef __attribute__((ext_vector_type(4))) float f32x4;

static __device__ __forceinline__ unsigned short f2bf(float f){
  __hip_bfloat16 h = __float2bfloat16(f);
  return *reinterpret_cast<unsigned short*>(&h);
}
static __device__ __forceinline__ float bflo(unsigned v){
  return __uint_as_float(v << 16);
}
static __device__ __forceinline__ float bfhi(unsigned v){
  return __uint_as_float(v & 0xFFFF0000u);
}
static __device__ __forceinline__ float bf2f(unsigned short u){
  return __uint_as_float(((unsigned)u) << 16);
}
static __device__ __forceinline__ short8v pack8(f32x4 L, f32x4 H){
  short8v r;
  r[0]=(short)f2bf(L[0]); r[1]=(short)f2bf(L[1]); r[2]=(short)f2bf(L[2]); r[3]=(short)f2bf(L[3]);
  r[4]=(short)f2bf(H[0]); r[5]=(short)f2bf(H[1]); r[6]=(short)f2bf(H[2]); r[7]=(short)f2bf(H[3]);
  return r;
}

// ---------------- transpose x: (16,3,N1) f32 -> xTb (N1, 16, 4) bf16 ----
__global__ __launch_bounds__(256) void transpose_x_kernel(
    const float* __restrict__ x, unsigned short* __restrict__ xTb)
{
  __shared__ float tile[48][65];
  int n0 = blockIdx.x * 64;
  int tid = threadIdx.x;
  int i = tid & 63;
  for (int rr = tid >> 6; rr < 48; rr += 4)
    tile[rr][i] = x[(size_t)rr * N1C + n0 + i];
  __syncthreads();
  for (int j = tid; j < 64*64; j += 256){
    int ii = j >> 6, bc = j & 63, b = bc >> 2, c = bc & 3;
    float v = (c < 3) ? tile[b*3 + c][ii] : 0.f;
    xTb[(size_t)n0 * 64 + j] = f2bf(v);
  }
}

// ---------------- A[n,k,t] = (relu(off @ w1 + b1) @ w2 + b2) ----------------
__global__ __launch_bounds__(256) void compute_A_kernel(
    const float* __restrict__ pos_in, const float* __restrict__ pos_out,
    const int* __restrict__ idx,
    const float* __restrict__ w1, const float* __restrict__ b1,
    const float* __restrict__ w2, const float* __restrict__ b2,
    float* __restrict__ Abuf)
{
  int g = blockIdx.x * 256 + threadIdx.x;
  if (g >= N2C * 9) return;
  int n = g / 9;
  int p = idx[g];
  float o0 = pos_in[2*p]   - pos_out[2*n];
  float o1 = pos_in[2*p+1] - pos_out[2*n+1];
  float A[9];
  #pragma unroll
  for (int t = 0; t < 9; t++) A[t] = b2[t];
  #pragma unroll
  for (int j = 0; j < 16; j++){
    float h = fmaxf(fmaf(o0, w1[j], fmaf(o1, w1[16+j], b1[j])), 0.f);
    #pragma unroll
    for (int t = 0; t < 9; t++) A[t] = fmaf(h, w2[j*9 + t], A[t]);
  }
  #pragma unroll
  for (int t = 0; t < 9; t++) Abuf[(size_t)g*9 + t] = A[t];
}

// ------ W (o,c,t) f32 -> Wb bf16. mode0: linear pad; mode1: t-major ------
__global__ __launch_bounds__(256) void wcvt_kernel(
    const float* __restrict__ W, unsigned short* __restrict__ Wb,
    int total, int K, int KW, int mode)
{
  int i = blockIdx.x * 256 + threadIdx.x;
  if (i >= total) return;
  int o = i / KW, r = i % KW;
  float v;
  if (mode == 0){
    v = (r < K) ? W[o*K + r] : 0.f;
  } else {
    int t = r >> 5, c = r & 31;
    v = W[o*288 + c*9 + t];
  }
  Wb[i] = f2bf(v);
}

// ======== conv1 path (small CIN), linear k-layout ========
template<int CIN, int CINP, int COUT, int NPB, bool AFFINE>
__global__ __launch_bounds__(256) void conv_mfma_kernel(
    const unsigned short* __restrict__ in, const int* __restrict__ idx,
    const float* __restrict__ Abuf, const unsigned short* __restrict__ Wb,
    const float* __restrict__ bias,
    const float* __restrict__ scale, const float* __restrict__ shift,
    unsigned short* __restrict__ out, float* __restrict__ gpart)
{
  constexpr int K    = CIN * 9;
  constexpr int KW   = (K < 32) ? 32 : K;
  constexpr int KROW = (K < 32) ? 48 : 296;
  constexpr int CHUNKS = KW / 32;
  constexpr int OT   = COUT / 16;
  constexpr int HP   = CINP / 2;
  constexpr int PPT  = 16 * HP;

  __shared__ alignas(16) unsigned short Tb[NPB * 16 * KROW];
  __shared__ float As[NPB * 81];
  __shared__ int   Ip[NPB * 9];
  __shared__ float Sw[4 * COUT];
  __shared__ float Sq[4 * COUT];

  int n0 = blockIdx.x * NPB;
  int tid = threadIdx.x;
  for (int i = tid; i < NPB*81; i += 256) As[i] = Abuf[(size_t)n0*81 + i];
  if (tid < NPB*9) Ip[tid] = idx[n0*9 + tid];
  for (int i = tid; i < 4*COUT; i += 256){ Sw[i] = 0.f; Sq[i] = 0.f; }
  if (K < 32){
    for (int i = tid; i < NPB*16*KROW/2; i += 256) ((unsigned*)Tb)[i] = 0u;
  }
  __syncthreads();

  for (int u = tid; u < NPB*PPT; u += 256){
    int ni = u / PPT, loc = u % PPT;
    int b = loc / HP, c2 = loc % HP;
    const float* As_n = As + ni*81;
    const int*   ip   = Ip + ni*9;
    float scx=1.f, shx=0.f, scy=1.f, shy=0.f;
    if (AFFINE){
      scx = scale[2*c2];   shx = shift[2*c2];
      scy = scale[2*c2+1]; shy = shift[2*c2+1];
    }
    float fx[9], fy[9];
    #pragma unroll
    for (int k = 0; k < 9; k++){
      unsigned v = *(const unsigned*)(in + ((size_t)ip[k]*16 + b)*CINP + 2*c2);
      float x0 = bflo(v), y0 = bfhi(v);
      if (AFFINE){
        x0 = fmaxf(fmaf(x0, scx, shx), 0.f);
        y0 = fmaxf(fmaf(y0, scy, shy), 0.f);
      }
      fx[k] = x0; fy[k] = y0;
    }
    unsigned short e[18];
    #pragma unroll
    for (int t = 0; t < 9; t++){
      float s0 = 0.f, s1 = 0.f;
      #pragma unroll
      for (int k = 0; k < 9; k++){
        float a = As_n[k*9 + t];
        s0 = fmaf(fx[k], a, s0);
        s1 = fmaf(fy[k], a, s1);
      }
      e[t] = f2bf(s0); e[9+t] = f2bf(s1);
    }
    unsigned* dst = (unsigned*)(Tb + (ni*16 + b)*KROW + 18*c2);
    #pragma unroll
    for (int j = 0; j < 9; j++) dst[j] = (unsigned)e[2*j] | ((unsigned)e[2*j+1] << 16);
  }
  __syncthreads();

  int w = tid >> 6, l = tid & 63, lr = l & 15, lg = l >> 4;
  float smr[4] = {0,0,0,0}, sqr[4] = {0,0,0,0};
  int oBase = 0;
  for (int wi = w; wi < NPB*OT; wi += 4){
    int ni = wi / OT, ot = wi % OT;
    oBase = 16*ot + 4*lg;
    f32x4 acc;
    #pragma unroll
    for (int r = 0; r < 4; r++) acc[r] = bias[oBase + r];
    const short8v* ap = (const short8v*)(Wb + (size_t)(16*ot + lr)*KW) + lg;
    const short8v* bp = (const short8v*)(Tb + (ni*16 + lr)*KROW) + lg;
    #pragma unroll
    for (int kk = 0; kk < CHUNKS; kk++)
      acc = __builtin_amdgcn_mfma_f32_16x16x32_bf16(ap[kk*4], bp[kk*4], acc, 0, 0, 0);
    ushort4 o4;
    o4.x = f2bf(acc[0]); o4.y = f2bf(acc[1]); o4.z = f2bf(acc[2]); o4.w = f2bf(acc[3]);
    *(ushort4*)(out + ((size_t)(n0 + ni)*16 + lr)*COUT + oBase) = o4;
    #pragma unroll
    for (int r = 0; r < 4; r++){
      smr[r] += acc[r];
      sqr[r] = fmaf(acc[r], acc[r], sqr[r]);
    }
  }
  #pragma unroll
  for (int m = 1; m < 16; m <<= 1){
    #pragma unroll
    for (int r = 0; r < 4; r++){
      smr[r] += __shfl_xor(smr[r], m);
      sqr[r] += __shfl_xor(sqr[r], m);
    }
  }
  if (lr == 0){
    #pragma unroll
    for (int r = 0; r < 4; r++){
      Sw[w*COUT + oBase + r] = smr[r];
      Sq[w*COUT + oBase + r] = sqr[r];
    }
  }
  __syncthreads();
  for (int o = tid; o < COUT; o += 256){
    float sm = Sw[o] + Sw[COUT + o] + Sw[2*COUT + o] + Sw[3*COUT + o];
    float sq = Sq[o] + Sq[COUT + o] + Sq[2*COUT + o] + Sq[3*COUT + o];
    gpart[(size_t)blockIdx.x * 2*COUT + o] = sm;
    gpart[(size_t)blockIdx.x * 2*COUT + COUT + o] = sq;
  }
}

// ======== conv2/3: zero-staging taps + W in LDS + k-interleaved prefetch ====
// Prefetch of point p+1's gather row k is issued immediately after KSTEP k
// consumes rv_k (WAR reuse, no extra registers) — each load gets the rest
// of taps + pack + MFMA as latency cover.

#define AWRITE(A0,A1) { int k_ = l/9, t_ = l - k_*9; Aw[k_*12 + t_] = (A0); \
    if (l < 17){ int j_ = l + 64; int k2_ = j_/9, t2_ = j_ - k2_*9; Aw[k2_*12 + t2_] = (A1); } }

#define KSTEP(RV, K) { \
    f32x4 fL_, fH_; \
    fL_[0]=bflo(RV.x); fL_[1]=bfhi(RV.x); fL_[2]=bflo(RV.y); fL_[3]=bfhi(RV.y); \
    fH_[0]=bflo(RV.z); fH_[1]=bfhi(RV.z); fH_[2]=bflo(RV.w); fH_[3]=bfhi(RV.w); \
    fL_ = fL_ * scL + shL; fH_ = fH_ * scH + shH; \
    fL_[0]=fmaxf(fL_[0],0.f); fL_[1]=fmaxf(fL_[1],0.f); \
    fL_[2]=fmaxf(fL_[2],0.f); fL_[3]=fmaxf(fL_[3],0.f); \
    fH_[0]=fmaxf(fH_[0],0.f); fH_[1]=fmaxf(fH_[1],0.f); \
    fH_[2]=fmaxf(fH_[2],0.f); fH_[3]=fmaxf(fH_[3],0.f); \
    f32x4 a03_ = *(const f32x4*)(Aw + (K)*12); \
    f32x4 a47_ = *(const f32x4*)(Aw + (K)*12 + 4); \
    float a8_ = Aw[(K)*12 + 8]; \
    tL0 += fL_ * a03_[0]; tH0 += fH_ * a03_[0]; \
    tL1 += fL_ * a03_[1]; tH1 += fH_ * a03_[1]; \
    tL2 += fL_ * a03_[2]; tH2 += fH_ * a03_[2]; \
    tL3 += fL_ * a03_[3]; tH3 += fH_ * a03_[3]; \
    tL4 += fL_ * a47_[0]; tH4 += fH_ * a47_[0]; \
    tL5 += fL_ * a47_[1]; tH5 += fH_ * a47_[1]; \
    tL6 += fL_ * a47_[2]; tH6 += fH_ * a47_[2]; \
    tL7 += fL_ * a47_[3]; tH7 += fH_ * a47_[3]; \
    tL8 += fL_ * a8_;     tH8 += fH_ * a8_; }

#define TAPS_DECL \
    f32x4 tL0={0,0,0,0},tL1={0,0,0,0},tL2={0,0,0,0},tL3={0,0,0,0},tL4={0,0,0,0}, \
          tL5={0,0,0,0},tL6={0,0,0,0},tL7={0,0,0,0},tL8={0,0,0,0}; \
    f32x4 tH0={0,0,0,0},tH1={0,0,0,0},tH2={0,0,0,0},tH3={0,0,0,0},tH4={0,0,0,0}, \
          tH5={0,0,0,0},tH6={0,0,0,0},tH7={0,0,0,0},tH8={0,0,0,0};

#define PACK_FRAGS \
    fr0 = pack8(tL0,tH0); fr1 = pack8(tL1,tH1); fr2 = pack8(tL2,tH2); \
    fr3 = pack8(tL3,tH3); fr4 = pack8(tL4,tH4); fr5 = pack8(tL5,tH5); \
    fr6 = pack8(tL6,tH6); fr7 = pack8(tL7,tH7); fr8 = pack8(tL8,tH8);

// taps on current rv, reloading each rv_k with next point's row k after use
#define TAPS_PACK_PF { TAPS_DECL \
    KSTEP(rv0,0) rv0 = *(const uint4*)(gbase + (size_t)j0*512); \
    KSTEP(rv1,1) rv1 = *(const uint4*)(gbase + (size_t)j1*512); \
    KSTEP(rv2,2) rv2 = *(const uint4*)(gbase + (size_t)j2*512); \
    KSTEP(rv3,3) rv3 = *(const uint4*)(gbase + (size_t)j3*512); \
    KSTEP(rv4,4) rv4 = *(const uint4*)(gbase + (size_t)j4*512); \
    KSTEP(rv5,5) rv5 = *(const uint4*)(gbase + (size_t)j5*512); \
    KSTEP(rv6,6) rv6 = *(const uint4*)(gbase + (size_t)j6*512); \
    KSTEP(rv7,7) rv7 = *(const uint4*)(gbase + (size_t)j7*512); \
    KSTEP(rv8,8) rv8 = *(const uint4*)(gbase + (size_t)j8*512); \
    PACK_FRAGS }

#define TAPS_PACK_LAST { TAPS_DECL \
    KSTEP(rv0,0) KSTEP(rv1,1) KSTEP(rv2,2) KSTEP(rv3,3) KSTEP(rv4,4) \
    KSTEP(rv5,5) KSTEP(rv6,6) KSTEP(rv7,7) KSTEP(rv8,8) \
    PACK_FRAGS }

#define NEXT_META(NWSN) { \
    const int* ipN_ = idx + (size_t)(NWSN)*9; \
    j0=ipN_[0]; j1=ipN_[1]; j2=ipN_[2]; j3=ipN_[3]; j4=ipN_[4]; \
    j5=ipN_[5]; j6=ipN_[6]; j7=ipN_[7]; j8=ipN_[8]; \
    const float* ApN_ = Abuf + (size_t)(NWSN)*81; \
    aN0 = ApN_[l]; aN1 = (l < 17) ? ApN_[64 + l] : 0.f; }

#define MFMA_STATS(NWSC) { \
    _Pragma("unroll") \
    for (int ot = 0; ot < OT; ot++){ \
      int oBase = 16*ot + 4*cg; \
      f32x4 a3; \
      a3[0]=bias[oBase]; a3[1]=bias[oBase+1]; a3[2]=bias[oBase+2]; a3[3]=bias[oBase+3]; \
      const short8v* ap_ = (const short8v*)(Wl + (size_t)(16*ot + b)*WROW) + cg; \
      a3 = __builtin_amdgcn_mfma_f32_16x16x32_bf16(ap_[0],  fr0, a3, 0, 0, 0); \
      a3 = __builtin_amdgcn_mfma_f32_16x16x32_bf16(ap_[4],  fr1, a3, 0, 0, 0); \
      a3 = __builtin_amdgcn_mfma_f32_16x16x32_bf16(ap_[8],  fr2, a3, 0, 0, 0); \
      a3 = __builtin_amdgcn_mfma_f32_16x16x32_bf16(ap_[12], fr3, a3, 0, 0, 0); \
      a3 = __builtin_amdgcn_mfma_f32_16x16x32_bf16(ap_[16], fr4, a3, 0, 0, 0); \
      a3 = __builtin_amdgcn_mfma_f32_16x16x32_bf16(ap_[20], fr5, a3, 0, 0, 0); \
      a3 = __builtin_amdgcn_mfma_f32_16x16x32_bf16(ap_[24], fr6, a3, 0, 0, 0); \
      a3 = __builtin_amdgcn_mfma_f32_16x16x32_bf16(ap_[28], fr7, a3, 0, 0, 0); \
      a3 = __builtin_amdgcn_mfma_f32_16x16x32_bf16(ap_[32], fr8, a3, 0, 0, 0); \
      ushort4 o4_; \
      o4_.x = f2bf(a3[0]); o4_.y = f2bf(a3[1]); o4_.z = f2bf(a3[2]); o4_.w = f2bf(a3[3]); \
      *(ushort4*)(out + ((size_t)(NWSC)*16 + b)*COUT + oBase) = o4_; \
      if (ot==0){ sm0 += a3; sq0 += a3*a3; } \
      else if (ot==1){ sm1 += a3; sq1 += a3*a3; } \
      else if (ot==2){ sm2 += a3; sq2 += a3*a3; } \
      else { sm3 += a3; sq3 += a3*a3; } } }

template<int COUT>
__global__ __launch_bounds__(256, 2) void conv_wave_kernel(
    const unsigned short* __restrict__ in, const int* __restrict__ idx,
    const float* __restrict__ Abuf, const unsigned short* __restrict__ Wb,
    const float* __restrict__ bias,
    const float* __restrict__ scale, const float* __restrict__ shift,
    unsigned short* __restrict__ out, float* __restrict__ gpart)
{
  constexpr int NPB  = 4;              // waves per block
  constexpr int PPW  = 4;              // points per wave
  constexpr int OT   = COUT / 16;
  constexpr int WROW = 296;            // LDS W row stride (shorts) — 2-way banks
  constexpr int USZ  = 128;

  __shared__ alignas(16) unsigned short Wl[COUT * WROW];
  __shared__ alignas(16) float U[NPB * USZ];

  int tid = threadIdx.x;
  int w = tid >> 6, l = tid & 63;
  int base = blockIdx.x * (NPB*PPW) + w * PPW;
  int b = l & 15, cg = l >> 4;

  // --- cooperative W stage ---
  for (int j = tid; j < COUT*36; j += 256){
    int o = j / 36, c = j % 36;
    *(uint4*)(Wl + (size_t)o*WROW + c*8) = *(const uint4*)(Wb + (size_t)o*288 + c*8);
  }

  const unsigned short* gbase = in + b*32 + cg*8;
  float* Aw = U + w * USZ;

  float4 scLf = *(const float4*)(scale + cg*8);
  float4 scHf = *(const float4*)(scale + cg*8 + 4);
  float4 shLf = *(const float4*)(shift + cg*8);
  float4 shHf = *(const float4*)(shift + cg*8 + 4);
  f32x4 scL; scL[0]=scLf.x; scL[1]=scLf.y; scL[2]=scLf.z; scL[3]=scLf.w;
  f32x4 shL; shL[0]=shLf.x; shL[1]=shLf.y; shL[2]=shLf.z; shL[3]=shLf.w;
  f32x4 scH; scH[0]=scHf.x; scH[1]=scHf.y; scH[2]=scHf.z; scH[3]=scHf.w;
  f32x4 shH; shH[0]=shHf.x; shH[1]=shHf.y; shH[2]=shHf.z; shH[3]=shHf.w;

  __syncthreads();   // W staged

  f32x4 sm0={0,0,0,0}, sm1={0,0,0,0}, sm2={0,0,0,0}, sm3={0,0,0,0};
  f32x4 sq0={0,0,0,0}, sq1={0,0,0,0}, sq2={0,0,0,0}, sq3={0,0,0,0};
  uint4 rv0,rv1,rv2,rv3,rv4,rv5,rv6,rv7,rv8;
  short8v fr0,fr1,fr2,fr3,fr4,fr5,fr6,fr7,fr8;
  int j0,j1,j2,j3,j4,j5,j6,j7,j8;
  float aN0, aN1;

  // ---- prologue: point 0 full load ----
  int nws0 = __builtin_amdgcn_readfirstlane(base + 0);
  NEXT_META(nws0);
  rv0 = *(const uint4*)(gbase + (size_t)j0*512);
  rv1 = *(const uint4*)(gbase + (size_t)j1*512);
  rv2 = *(const uint4*)(gbase + (size_t)j2*512);
  rv3 = *(const uint4*)(gbase + (size_t)j3*512);
  rv4 = *(const uint4*)(gbase + (size_t)j4*512);
  rv5 = *(const uint4*)(gbase + (size_t)j5*512);
  rv6 = *(const uint4*)(gbase + (size_t)j6*512);
  rv7 = *(const uint4*)(gbase + (size_t)j7*512);
  rv8 = *(const uint4*)(gbase + (size_t)j8*512);
  AWRITE(aN0, aN1);

  // ---- p0: taps(p0) with embedded prefetch of p1 ----
  int nws1 = __builtin_amdgcn_readfirstlane(base + 1);
  NEXT_META(nws1);
  TAPS_PACK_PF;
  __builtin_amdgcn_sched_barrier(0);
  MFMA_STATS(nws0);
  AWRITE(aN0, aN1);

  // ---- p1 ----
  int nws2 = __builtin_amdgcn_readfirstlane(base + 2);
  NEXT_META(nws2);
  TAPS_PACK_PF;
  __builtin_amdgcn_sched_barrier(0);
  MFMA_STATS(nws1);
  AWRITE(aN0, aN1);

  // ---- p2 ----
  int nws3 = __builtin_amdgcn_readfirstlane(base + 3);
  NEXT_META(nws3);
  TAPS_PACK_PF;
  __builtin_amdgcn_sched_barrier(0);
  MFMA_STATS(nws2);
  AWRITE(aN0, aN1);

  // ---- p3 (last) ----
  TAPS_PACK_LAST;
  MFMA_STATS(nws3);

  // ---- stats: reduce over b lanes; U slot (A dead) holds partials ----
  #pragma unroll
  for (int ot = 0; ot < OT; ot++){
    f32x4 s = (ot==0) ? sm0 : ((ot==1) ? sm1 : ((ot==2) ? sm2 : sm3));
    f32x4 q = (ot==0) ? sq0 : ((ot==1) ? sq1 : ((ot==2) ? sq2 : sq3));
    #pragma unroll
    for (int m = 1; m < 16; m <<= 1){
      #pragma unroll
      for (int r = 0; r < 4; r++){
        s[r] += __shfl_xor(s[r], m);
        q[r] += __shfl_xor(q[r], m);
      }
    }
    if (b == 0){
      int oBase = 16*ot + 4*cg;
      #pragma unroll
      for (int r = 0; r < 4; r++){
        U[w*USZ + oBase + r]        = s[r];
        U[w*USZ + COUT + oBase + r] = q[r];
      }
    }
  }
  __syncthreads();
  for (int o = tid; o < COUT; o += 256){
    float smv = U[o] + U[USZ + o] + U[2*USZ + o] + U[3*USZ + o];
    float sqv = U[COUT + o] + U[USZ + COUT + o] + U[2*USZ + COUT + o] + U[3*USZ + COUT + o];
    gpart[(size_t)blockIdx.x * 2*COUT + o] = smv;
    gpart[(size_t)blockIdx.x * 2*COUT + COUT + o] = sqv;
  }
}

#undef AWRITE
#undef KSTEP
#undef TAPS_DECL
#undef PACK_FRAGS
#undef TAPS_PACK_PF
#undef TAPS_PACK_LAST
#undef NEXT_META
#undef MFMA_STATS

// ---------------- finalize BN ----------------
__global__ __launch_bounds__(256) void bn_finalize_kernel(
    const float* __restrict__ gpart, int NB, int C,
    const float* __restrict__ g, const float* __restrict__ bb,
    float* __restrict__ sc, float* __restrict__ sh, float invN)
{
  int c = blockIdx.x;
  float sm = 0.f, sq = 0.f;
  for (int i = threadIdx.x; i < NB; i += 256){
    sm += gpart[(size_t)i*2*C + c];
    sq += gpart[(size_t)i*2*C + C + c];
  }
  #pragma unroll
  for (int off = 32; off > 0; off >>= 1){
    sm += __shfl_down(sm, off);
    sq += __shfl_down(sq, off);
  }
  __shared__ float rs[8];
  int wd = threadIdx.x >> 6, ln = threadIdx.x & 63;
  if (ln == 0){ rs[wd] = sm; rs[4+wd] = sq; }
  __syncthreads();
  if (threadIdx.x == 0){
    float S = rs[0]+rs[1]+rs[2]+rs[3], Q = rs[4]+rs[5]+rs[6]+rs[7];
    float mean = S * invN;
    float var  = fmaxf(Q * invN - mean*mean, 0.f);
    float s = g[c] * rsqrtf(var + 1e-5f);
    sc[c] = s;
    sh[c] = bb[c] - mean * s;
  }
}

// ------------- BN3 + relu + max-pool + write (16,64,N3) f32 -------------
__global__ __launch_bounds__(256) void pool_kernel(
    const unsigned short* __restrict__ h3, const int* __restrict__ pidx,
    const float* __restrict__ sc, const float* __restrict__ sh,
    float* __restrict__ out)
{
  __shared__ float P[16][1024];
  int m0 = blockIdx.x * 16;
  int tid = threadIdx.x;
  for (int mi = 0; mi < 16; mi++){
    int m = m0 + mi;
    int p0 = pidx[m*4+0], p1 = pidx[m*4+1], p2 = pidx[m*4+2], p3 = pidx[m*4+3];
    #pragma unroll
    for (int q = 0; q < 4; q++){
      int bo = tid + q*256;
      int o = bo & 63;
      float s = sc[o], h = sh[o];
      float v0 = fmaf(bf2f(h3[(size_t)p0*1024 + bo]), s, h);
      float v1 = fmaf(bf2f(h3[(size_t)p1*1024 + bo]), s, h);
      float v2 = fmaf(bf2f(h3[(size_t)p2*1024 + bo]), s, h);
      float v3 = fmaf(bf2f(h3[(size_t)p3*1024 + bo]), s, h);
      P[mi][bo] = fmaxf(fmaxf(fmaxf(v0,v1), fmaxf(v2,v3)), 0.f);
    }
  }
  __syncthreads();
  #pragma unroll
  for (int w = 0; w < 4; w++){
    int r = tid + w*256;
    float* dst = out + (size_t)r*N3C + m0;
    #pragma unroll
    for (int mi = 0; mi < 16; mi++) dst[mi] = P[mi][r];
  }
}

// ---------------- launch ----------------
extern "C" void kernel_launch(void* const* d_in, const int* in_sizes, int n_in,
                              void* d_out, int out_size, void* d_ws, size_t ws_size,
                              hipStream_t stream)
{
  const float* x    = (const float*)d_in[0];
  const float* l1   = (const float*)d_in[1];
  const float* l2   = (const float*)d_in[2];
  const int* knn1   = (const int*)d_in[4];
  const int* knn2   = (const int*)d_in[5];
  const int* knn3   = (const int*)d_in[6];
  const int* pidx   = (const int*)d_in[7];

  const float* c1_w1 = (const float*)d_in[8];
  const float* c1_b1 = (const float*)d_in[9];
  const float* c1_w2 = (const float*)d_in[10];
  const float* c1_b2 = (const float*)d_in[11];
  const float* c1_k  = (const float*)d_in[12];
  const float* c1_bs = (const float*)d_in[13];
  const float* c2_w1 = (const float*)d_in[14];
  const float* c2_b1 = (const float*)d_in[15];
  const float* c2_w2 = (const float*)d_in[16];
  const float* c2_b2 = (const float*)d_in[17];
  const float* c2_k  = (const float*)d_in[18];
  const float* c2_bs = (const float*)d_in[19];
  const float* c3_w1 = (const float*)d_in[20];
  const float* c3_b1 = (const float*)d_in[21];
  const float* c3_w2 = (const float*)d_in[22];
  const float* c3_b2 = (const float*)d_in[23];
  const float* c3_k  = (const float*)d_in[24];
  const float* c3_bs = (const float*)d_in[25];
  const float* bn1_g = (const float*)d_in[26];
  const float* bn1_b = (const float*)d_in[27];
  const float* bn2_g = (const float*)d_in[28];
  const float* bn2_b = (const float*)d_in[29];
  const float* bn3_g = (const float*)d_in[30];
  const float* bn3_b = (const float*)d_in[31];

  char* ws = (char*)d_ws;
  unsigned short* xTb = (unsigned short*)(ws + 0);
  unsigned short* h1  = (unsigned short*)(ws + 6422528);
  unsigned short* h2  = (unsigned short*)(ws + 19267584);
  unsigned short* h3  = (unsigned short*)(ws + 32112640);
  float* Abuf         = (float*)(ws + 57802752);
  float* gpart        = (float*)(ws + 61867008);
  unsigned short* wb1 = (unsigned short*)(ws + 65078272);
  unsigned short* wb2 = (unsigned short*)(ws + 65081344);
  unsigned short* wb3 = (unsigned short*)(ws + 65099776);
  float* sc1 = (float*)(ws + 65137664); float* sh1 = sc1 + 32;
  float* sc2 = sh1 + 32;                float* sh2 = sc2 + 32;
  float* sc3 = sh2 + 32;                float* sh3 = sc3 + 64;

  const float invN = 1.0f / (float)(N2C * 16);
  const int ablocks = (N2C * 9 + 255) / 256;
  const int cwblocks = N2C / 16;   // 784

  transpose_x_kernel<<<N1C/64, 256, 0, stream>>>(x, xTb);
  wcvt_kernel<<<(32*32 + 255)/256, 256, 0, stream>>>(c1_k, wb1, 32*32, 27, 32, 0);
  wcvt_kernel<<<(32*288 + 255)/256, 256, 0, stream>>>(c2_k, wb2, 32*288, 288, 288, 1);
  wcvt_kernel<<<(64*288 + 255)/256, 256, 0, stream>>>(c3_k, wb3, 64*288, 288, 288, 1);

  // conv1
  compute_A_kernel<<<ablocks, 256, 0, stream>>>(l1, l2, knn1, c1_w1, c1_b1, c1_w2, c1_b2, Abuf);
  conv_mfma_kernel<3, 4, 32, 8, false><<<N2C/8, 256, 0, stream>>>(
      xTb, knn1, Abuf, wb1, c1_bs, nullptr, nullptr, h1, gpart);
  bn_finalize_kernel<<<32, 256, 0, stream>>>(gpart, N2C/8, 32, bn1_g, bn1_b, sc1, sh1, invN);

  // conv2
  compute_A_kernel<<<ablocks, 256, 0, stream>>>(l2, l2, knn2, c2_w1, c2_b1, c2_w2, c2_b2, Abuf);
  conv_wave_kernel<32><<<cwblocks, 256, 0, stream>>>(
      h1, knn2, Abuf, wb2, c2_bs, sc1, sh1, h2, gpart);
  bn_finalize_kernel<<<32, 256, 0, stream>>>(gpart, cwblocks, 32, bn2_g, bn2_b, sc2, sh2, invN);

  // conv3
  compute_A_kernel<<<ablocks, 256, 0, stream>>>(l2, l2, knn3, c3_w1, c3_b1, c3_w2, c3_b2, Abuf);
  conv_wave_kernel<64><<<cwblocks, 256, 0, stream>>>(
      h2, knn3, Abuf, wb3, c3_bs, sc2, sh2, h3, gpart);
  bn_finalize_kernel<<<64, 256, 0, stream>>>(gpart, cwblocks, 64, bn3_g, bn3_b, sc3, sh3, invN);

  pool_kernel<<<N3C/16, 256, 0, stream>>>(h3, pidx, sc3, sh3, (float*)d_out);
}